// Round 1
// baseline (1693.098 us; speedup 1.0000x reference)
//
#include <hip/hip_runtime.h>
#include <stdint.h>

typedef unsigned short u16;
typedef __bf16 bf16x8 __attribute__((ext_vector_type(8)));
typedef float f32x4 __attribute__((ext_vector_type(4)));

#define AS1 __attribute__((address_space(1)))
#define AS3 __attribute__((address_space(3)))

// Problem constants
static constexpr int S = 512, Bb = 8, D = 1024, V = 32000, L = 6, NH = 16, HD = 64;
static constexpr int N = S * Bb;        // 4096 token rows
static constexpr int D3 = 3 * D;        // 3072

__device__ __forceinline__ u16 f2bf(float f) {
  union { float f; uint32_t u; } c; c.f = f;
  uint32_t r = c.u + 0x7FFFu + ((c.u >> 16) & 1u);
  return (u16)(r >> 16);
}

__device__ __forceinline__ void gload16(const void* g, void* l) {
  __builtin_amdgcn_global_load_lds((const AS1 void*)g, (AS3 void*)l, 16, 0, 0);
}

// ---------------- generic f32 -> bf16 convert (vectorized) ----------------
__global__ __launch_bounds__(256) void cvt_kernel(const float* __restrict__ in,
                                                  u16* __restrict__ out, int n4) {
  int idx = blockIdx.x * 256 + threadIdx.x;
  if (idx < n4) {
    float4 v = ((const float4*)in)[idx];
    ushort4 o;
    o.x = f2bf(v.x); o.y = f2bf(v.y); o.z = f2bf(v.z); o.w = f2bf(v.w);
    ((ushort4*)out)[idx] = o;
  }
}

// ---------------- embed_mean transpose + convert (1024x1024) ----------------
__global__ __launch_bounds__(256) void transpose_cvt(const float* __restrict__ in,
                                                     u16* __restrict__ out) {
  __shared__ float t[32][33];
  const int bx = blockIdx.x * 32, by = blockIdx.y * 32;
  const int tid = threadIdx.x;
  const int c = tid & 31;
#pragma unroll
  for (int r = tid >> 5; r < 32; r += 8)
    t[r][c] = in[(size_t)(by + r) * D + bx + c];
  __syncthreads();
#pragma unroll
  for (int r = tid >> 5; r < 32; r += 8)
    out[(size_t)(bx + r) * D + by + c] = f2bf(t[c][r]);
}

// ---------------- embedding gather * sqrt(D) -> bf16 ----------------
__global__ __launch_bounds__(256) void gather_kernel(const int* __restrict__ src,
                                                     const float* __restrict__ emb,
                                                     u16* __restrict__ xe) {
  int idx = blockIdx.x * 256 + threadIdx.x;        // one thread = 4 elems
  int n = idx >> 8, d4 = (idx & 255) * 4;
  int tok = src[n];
  float4 v = *(const float4*)(emb + (size_t)tok * D + d4);
  ushort4 o;
  o.x = f2bf(v.x * 32.f); o.y = f2bf(v.y * 32.f);
  o.z = f2bf(v.z * 32.f); o.w = f2bf(v.w * 32.f);
  *(ushort4*)(xe + (size_t)n * D + d4) = o;
}

// ---------------- add sinusoidal PE; produce f32 master + bf16 copy ----------------
__global__ __launch_bounds__(256) void pe_kernel(const float* __restrict__ t,
                                                 float* __restrict__ x,
                                                 u16* __restrict__ xb) {
  int idx = blockIdx.x * 256 + threadIdx.x;        // over N*D
  int d = idx & (D - 1);
  int s = idx >> 13;                               // n = idx>>10, s = n>>3
  float freq = __expf(-(float)(d & ~1) * (9.210340371976184f / 1024.f));
  float a = (float)s * freq;
  float p = (d & 1) ? __cosf(a) : __sinf(a);
  float v = t[idx] + p;
  x[idx] = v;
  xb[idx] = f2bf(v);
}

// ---------------- fused residual-add + LayerNorm; f32 master + bf16 copy ----------------
__global__ __launch_bounds__(256) void ln_kernel(const float* __restrict__ xold,
                                                 const float* __restrict__ delta,
                                                 const float* __restrict__ g,
                                                 const float* __restrict__ bb,
                                                 float* __restrict__ xnew,
                                                 u16* __restrict__ xbf) {
  const int row = blockIdx.x * 4 + (threadIdx.x >> 6);
  const int lane = threadIdx.x & 63;
  const float* xr = xold + (size_t)row * D;
  const float* dr = delta + (size_t)row * D;
  float v[16];
  float s = 0.f;
#pragma unroll
  for (int j = 0; j < 16; ++j) { v[j] = xr[j * 64 + lane] + dr[j * 64 + lane]; s += v[j]; }
  for (int off = 32; off; off >>= 1) s += __shfl_xor(s, off);
  float mu = s * (1.f / 1024.f);
  float s2 = 0.f;
#pragma unroll
  for (int j = 0; j < 16; ++j) { float dd = v[j] - mu; s2 += dd * dd; }
  for (int off = 32; off; off >>= 1) s2 += __shfl_xor(s2, off);
  float rstd = rsqrtf(s2 * (1.f / 1024.f) + 1e-5f);
#pragma unroll
  for (int j = 0; j < 16; ++j) {
    int c = j * 64 + lane;
    float y = (v[j] - mu) * rstd * g[c] + bb[c];
    xnew[(size_t)row * D + c] = y;
    xbf[(size_t)row * D + c] = f2bf(y);
  }
}

// ---------------- V transpose per (b,h): vtg[bh][d][s] = V[s][d] ----------------
__global__ __launch_bounds__(256) void vtrans_kernel(const u16* __restrict__ qkv,
                                                     u16* __restrict__ vtg) {
  __shared__ u16 t[64][72];
  const int st = blockIdx.x * 64;
  const int bh = blockIdx.y;
  const int b = bh >> 4, h = bh & 15;
  const int tid = threadIdx.x;
#pragma unroll
  for (int r = 0; r < 4; ++r) {
    int l = r * 1024 + tid * 4;
    int s = l >> 6, d = l & 63;
    ushort4 v = *(const ushort4*)(qkv + (size_t)((st + s) * Bb + b) * D3 + 2 * D + h * HD + d);
    *(ushort4*)&t[s][d] = v;
  }
  __syncthreads();
  u16* o = vtg + (size_t)bh * (HD * S) + st;
#pragma unroll
  for (int r = 0; r < 4; ++r) {
    int l = r * 1024 + tid * 4;
    int d = l >> 6, s = l & 63;
    ushort4 v;
    v.x = t[s][d]; v.y = t[s + 1][d]; v.z = t[s + 2][d]; v.w = t[s + 3][d];
    *(ushort4*)(o + (size_t)d * S + s) = v;
  }
}

// ---------------- GEMM: C[N,M] = A[N,K] @ B[M,K]^T (+bias)(+relu) ----------------
// 128x128 tile, BK=64, 4 waves (2x2 of 64x64), 16x16x32 bf16 MFMA. m97 structure.
template <int EPI, bool OBF>   // EPI: 0 none, 1 bias, 2 bias+relu. OBF: bf16 out else f32.
__global__ __launch_bounds__(256, 2) void gemm_bt(const u16* __restrict__ A,
                                                  const u16* __restrict__ B,
                                                  const float* __restrict__ bias,
                                                  void* __restrict__ Cout,
                                                  int Nr, int M, int K) {
  __shared__ u16 lA[8192];
  __shared__ u16 lB[8192];
  const int tid = threadIdx.x;
  const int lane = tid & 63;
  const int w = tid >> 6;
  const int wm = w >> 1, wn = w & 1;
  const int l15 = lane & 15, l4 = lane >> 4;
  const int row0 = blockIdx.y * 128, col0 = blockIdx.x * 128;

  const int sfl = tid * 8;            // bf16 elems; byte offset = tid*16 (linear per lane)
  const int srow = sfl >> 6;          // 0..31
  const int scol = sfl & 63;
  const u16* Ag = A + (size_t)(row0 + srow) * K + scol;
  const u16* Bg = B + (size_t)(col0 + srow) * K + scol;

  f32x4 acc[4][4] = {};

  for (int kt = 0; kt < K; kt += 64) {
#pragma unroll
    for (int r = 0; r < 4; ++r) {
      gload16(Ag + (size_t)r * 32 * K + kt, &lA[r * 2048 + sfl]);
      gload16(Bg + (size_t)r * 32 * K + kt, &lB[r * 2048 + sfl]);
    }
    asm volatile("s_waitcnt vmcnt(0)" ::: "memory");
    __syncthreads();
#pragma unroll
    for (int kk = 0; kk < 2; ++kk) {
      bf16x8 af[4], bfr[4];
#pragma unroll
      for (int i = 0; i < 4; ++i)
        af[i] = *(const bf16x8*)&lA[(wm * 64 + i * 16 + l15) * 64 + kk * 32 + l4 * 8];
#pragma unroll
      for (int i = 0; i < 4; ++i)
        bfr[i] = *(const bf16x8*)&lB[(wn * 64 + i * 16 + l15) * 64 + kk * 32 + l4 * 8];
#pragma unroll
      for (int i = 0; i < 4; ++i)
#pragma unroll
        for (int j = 0; j < 4; ++j)
          acc[i][j] = __builtin_amdgcn_mfma_f32_16x16x32_bf16(af[i], bfr[j], acc[i][j], 0, 0, 0);
    }
    __syncthreads();
  }

#pragma unroll
  for (int i = 0; i < 4; ++i) {
    const int rb = row0 + wm * 64 + i * 16 + l4 * 4;   // C row = (lane>>4)*4 + reg
#pragma unroll
    for (int j = 0; j < 4; ++j) {
      const int c = col0 + wn * 64 + j * 16 + l15;     // C col = lane&15
      float bv = 0.f;
      if constexpr (EPI >= 1) bv = bias[c];
#pragma unroll
      for (int q = 0; q < 4; ++q) {
        float v = acc[i][j][q] + bv;
        if constexpr (EPI == 2) v = fmaxf(v, 0.f);
        size_t o = (size_t)(rb + q) * M + c;
        if constexpr (OBF) ((u16*)Cout)[o] = f2bf(v);
        else ((float*)Cout)[o] = v;
      }
    }
  }
}

// ---------------- fused causal attention, one WG per (qtile, h, b) ----------------
// K and V^T staged fully in LDS; per-wave online softmax over 64-key chunks.
__global__ __launch_bounds__(256, 1) void attn_kernel(const u16* __restrict__ qkv,
                                                      const u16* __restrict__ vtg,
                                                      u16* __restrict__ att) {
  __shared__ u16 Kl[S * HD];        // [s][d]   64 KB
  __shared__ u16 Vt[HD * S];        // [d][s]   64 KB
  __shared__ u16 Pl[4][32 * 64];    // per-wave P scratch, 16 KB
  const int tid = threadIdx.x, lane = tid & 63, w = tid >> 6;
  const int qt = blockIdx.x, h = blockIdx.y, b = blockIdx.z;
  const int l15 = lane & 15, l4 = lane >> 4;

  {  // stage K (rows s, cols d) and Vt (linear copy)
    const int sfl = tid * 8;
#pragma unroll
    for (int r = 0; r < 16; ++r) {
      int l = r * 2048 + sfl;
      int s = l >> 6, d = l & 63;
      gload16(qkv + (size_t)(s * Bb + b) * D3 + D + h * HD + d, &Kl[l]);
    }
    const u16* vg = vtg + (size_t)(b * NH + h) * (HD * S);
#pragma unroll
    for (int r = 0; r < 16; ++r) {
      int l = r * 2048 + sfl;
      gload16(vg + l, &Vt[l]);
    }
  }
  asm volatile("s_waitcnt vmcnt(0)" ::: "memory");
  __syncthreads();

  const int qbase = qt * 128 + w * 32;
  bf16x8 qf[2][2];
#pragma unroll
  for (int fm = 0; fm < 2; ++fm)
#pragma unroll
    for (int kk = 0; kk < 2; ++kk) {
      int qs = qbase + fm * 16 + l15;
      qf[fm][kk] = *(const bf16x8*)(qkv + (size_t)(qs * Bb + b) * D3 + h * HD + kk * 32 + l4 * 8);
    }

  float m_run[2][4], l_run[2][4];
  f32x4 o[2][4] = {};
#pragma unroll
  for (int fm = 0; fm < 2; ++fm)
#pragma unroll
    for (int j = 0; j < 4; ++j) { m_run[fm][j] = -1e30f; l_run[fm][j] = 0.f; }

  const int nchunk = (qbase + 31) / 64 + 1;
  for (int ch = 0; ch < nchunk; ++ch) {
    f32x4 sc[2][4] = {};
#pragma unroll
    for (int kk = 0; kk < 2; ++kk) {
      bf16x8 kb[4];
#pragma unroll
      for (int fn = 0; fn < 4; ++fn)
        kb[fn] = *(const bf16x8*)&Kl[(ch * 64 + fn * 16 + l15) * 64 + kk * 32 + l4 * 8];
#pragma unroll
      for (int fm = 0; fm < 2; ++fm)
#pragma unroll
        for (int fn = 0; fn < 4; ++fn)
          sc[fm][fn] = __builtin_amdgcn_mfma_f32_16x16x32_bf16(qf[fm][kk], kb[fn], sc[fm][fn], 0, 0, 0);
    }
    // scale + causal mask + row max (rows r=l4*4+j, cols key=fn*16+l15)
    float pv[2][4][4], rm[2][4];
#pragma unroll
    for (int fm = 0; fm < 2; ++fm)
#pragma unroll
      for (int j = 0; j < 4; ++j) {
        float mx = -1e30f;
        int q_s = qbase + fm * 16 + l4 * 4 + j;
#pragma unroll
        for (int fn = 0; fn < 4; ++fn) {
          int k_s = ch * 64 + fn * 16 + l15;
          float vv = sc[fm][fn][j] * 0.125f;
          vv = (k_s <= q_s) ? vv : -1e30f;
          pv[fm][fn][j] = vv;
          mx = fmaxf(mx, vv);
        }
        rm[fm][j] = mx;
      }
    for (int off = 1; off <= 8; off <<= 1)
#pragma unroll
      for (int fm = 0; fm < 2; ++fm)
#pragma unroll
        for (int j = 0; j < 4; ++j)
          rm[fm][j] = fmaxf(rm[fm][j], __shfl_xor(rm[fm][j], off));
    float corr[2][4];
#pragma unroll
    for (int fm = 0; fm < 2; ++fm)
#pragma unroll
      for (int j = 0; j < 4; ++j) {
        float mn = fmaxf(m_run[fm][j], rm[fm][j]);
        corr[fm][j] = __expf(m_run[fm][j] - mn);
        m_run[fm][j] = mn;
      }
    float rs[2][4];
#pragma unroll
    for (int fm = 0; fm < 2; ++fm)
#pragma unroll
      for (int j = 0; j < 4; ++j) {
        float sum = 0.f;
#pragma unroll
        for (int fn = 0; fn < 4; ++fn) {
          float p = __expf(pv[fm][fn][j] - m_run[fm][j]);
          pv[fm][fn][j] = p;
          sum += p;
        }
        rs[fm][j] = sum;
      }
    for (int off = 1; off <= 8; off <<= 1)
#pragma unroll
      for (int fm = 0; fm < 2; ++fm)
#pragma unroll
        for (int j = 0; j < 4; ++j)
          rs[fm][j] += __shfl_xor(rs[fm][j], off);
#pragma unroll
    for (int fm = 0; fm < 2; ++fm)
#pragma unroll
      for (int j = 0; j < 4; ++j)
        l_run[fm][j] = l_run[fm][j] * corr[fm][j] + rs[fm][j];
#pragma unroll
    for (int fm = 0; fm < 2; ++fm)
#pragma unroll
      for (int fd = 0; fd < 4; ++fd)
#pragma unroll
        for (int j = 0; j < 4; ++j) o[fm][fd][j] *= corr[fm][j];
    // write P (C-layout) to per-wave LDS, re-read in A-fragment layout
    u16* P = &Pl[w][0];
#pragma unroll
    for (int fm = 0; fm < 2; ++fm)
#pragma unroll
      for (int fn = 0; fn < 4; ++fn)
#pragma unroll
        for (int j = 0; j < 4; ++j)
          P[(fm * 16 + l4 * 4 + j) * 64 + fn * 16 + l15] = f2bf(pv[fm][fn][j]);
    asm volatile("" ::: "memory");
#pragma unroll
    for (int kk = 0; kk < 2; ++kk) {
      bf16x8 pa[2];
#pragma unroll
      for (int fm = 0; fm < 2; ++fm)
        pa[fm] = *(const bf16x8*)&P[(fm * 16 + l15) * 64 + kk * 32 + l4 * 8];
#pragma unroll
      for (int fd = 0; fd < 4; ++fd) {
        bf16x8 vb = *(const bf16x8*)&Vt[(fd * 16 + l15) * S + ch * 64 + kk * 32 + l4 * 8];
#pragma unroll
        for (int fm = 0; fm < 2; ++fm)
          o[fm][fd] = __builtin_amdgcn_mfma_f32_16x16x32_bf16(pa[fm], vb, o[fm][fd], 0, 0, 0);
      }
    }
    asm volatile("" ::: "memory");
  }
#pragma unroll
  for (int fm = 0; fm < 2; ++fm)
#pragma unroll
    for (int fd = 0; fd < 4; ++fd)
#pragma unroll
      for (int j = 0; j < 4; ++j) {
        int s = qbase + fm * 16 + l4 * 4 + j;
        int d = h * HD + fd * 16 + l15;
        att[(size_t)(s * Bb + b) * D + d] = f2bf(o[fm][fd][j] / l_run[fm][j]);
      }
}

extern "C" void kernel_launch(void* const* d_in, const int* in_sizes, int n_in,
                              void* d_out, int out_size, void* d_ws, size_t ws_size,
                              hipStream_t stream) {
  const int* src = (const int*)d_in[0];
  const float* emb = (const float*)d_in[1];
  const float* em = (const float*)d_in[2];
  const float* qkvw = (const float*)d_in[3];
  const float* qkvb = (const float*)d_in[4];
  const float* ow = (const float*)d_in[5];
  const float* ob = (const float*)d_in[6];
  const float* w1 = (const float*)d_in[7];
  const float* b1 = (const float*)d_in[8];
  const float* w2 = (const float*)d_in[9];
  const float* b2 = (const float*)d_in[10];
  const float* ln1g = (const float*)d_in[11];
  const float* ln1b = (const float*)d_in[12];
  const float* ln2g = (const float*)d_in[13];
  const float* ln2b = (const float*)d_in[14];
  const float* decw = (const float*)d_in[15];
  const float* decb = (const float*)d_in[16];
  float* out = (float*)d_out;

  uint8_t* ws = (uint8_t*)d_ws;
  size_t off = 0;
  auto alloc = [&](size_t bytes) -> void* {
    void* p = ws + off;
    off += (bytes + 255) & ~(size_t)255;
    return p;
  };
  u16* decw_bf = (u16*)alloc((size_t)V * D * 2);          // 65.5 MB
  u16* lw_qkv  = (u16*)alloc((size_t)D3 * D * 2);         // 6.3 MB (per-layer reuse)
  u16* lw_o    = (u16*)alloc((size_t)D * D * 2);
  u16* lw_1    = (u16*)alloc((size_t)D * D * 2);
  u16* lw_2    = (u16*)alloc((size_t)D * D * 2);
  u16* em_bf   = (u16*)alloc((size_t)D * D * 2);
  u16* emT_bf  = (u16*)alloc((size_t)D * D * 2);
  u16* xe_bf   = (u16*)alloc((size_t)N * D * 2);
  float* x_f   = (float*)alloc((size_t)N * D * 4);
  u16* x_bf    = (u16*)alloc((size_t)N * D * 2);
  float* tmp_f = (float*)alloc((size_t)N * D * 4);
  u16* qkv_bf  = (u16*)alloc((size_t)N * D3 * 2);         // 25 MB
  u16* vtg     = (u16*)alloc((size_t)N * D * 2);
  u16* att_bf  = (u16*)alloc((size_t)N * D * 2);
  u16* h_bf    = (u16*)alloc((size_t)N * D * 2);
  u16* pred_bf = (u16*)alloc((size_t)N * D * 2);
  (void)ws_size; (void)in_sizes; (void)n_in; (void)out_size;  // total ~190 MB

  cvt_kernel<<<1024, 256, 0, stream>>>(em, em_bf, D * D / 4);
  transpose_cvt<<<dim3(32, 32), 256, 0, stream>>>(em, emT_bf);
  gather_kernel<<<N * D / 1024, 256, 0, stream>>>(src, emb, xe_bf);
  gemm_bt<0, false><<<dim3(D / 128, N / 128), 256, 0, stream>>>(xe_bf, em_bf, nullptr, tmp_f, N, D, D);
  pe_kernel<<<N * D / 256, 256, 0, stream>>>(tmp_f, x_f, x_bf);

  for (int l = 0; l < L; ++l) {
    cvt_kernel<<<D3 * D / 1024, 256, 0, stream>>>(qkvw + (size_t)l * D3 * D, lw_qkv, D3 * D / 4);
    cvt_kernel<<<D * D / 1024, 256, 0, stream>>>(ow + (size_t)l * D * D, lw_o, D * D / 4);
    cvt_kernel<<<D * D / 1024, 256, 0, stream>>>(w1 + (size_t)l * D * D, lw_1, D * D / 4);
    cvt_kernel<<<D * D / 1024, 256, 0, stream>>>(w2 + (size_t)l * D * D, lw_2, D * D / 4);

    gemm_bt<1, true><<<dim3(D3 / 128, N / 128), 256, 0, stream>>>(x_bf, lw_qkv, qkvb + l * D3, qkv_bf, N, D3, D);
    vtrans_kernel<<<dim3(S / 64, Bb * NH), 256, 0, stream>>>(qkv_bf, vtg);
    attn_kernel<<<dim3(S / 128, NH, Bb), 256, 0, stream>>>(qkv_bf, vtg, att_bf);
    gemm_bt<1, false><<<dim3(D / 128, N / 128), 256, 0, stream>>>(att_bf, lw_o, ob + l * D, tmp_f, N, D, D);
    ln_kernel<<<N / 4, 256, 0, stream>>>(x_f, tmp_f, ln1g + l * D, ln1b + l * D, x_f, x_bf);
    gemm_bt<2, true><<<dim3(D / 128, N / 128), 256, 0, stream>>>(x_bf, lw_1, b1 + l * D, h_bf, N, D, D);
    gemm_bt<1, false><<<dim3(D / 128, N / 128), 256, 0, stream>>>(h_bf, lw_2, b2 + l * D, tmp_f, N, D, D);
    ln_kernel<<<N / 4, 256, 0, stream>>>(x_f, tmp_f, ln2g + l * D, ln2b + l * D, x_f, x_bf);
  }

  gemm_bt<0, true><<<dim3(D / 128, N / 128), 256, 0, stream>>>(x_bf, emT_bf, nullptr, pred_bf, N, D, D);
  cvt_kernel<<<(size_t)V * D / 1024, 256, 0, stream>>>(decw, decw_bf, V * D / 4);
  gemm_bt<1, false><<<dim3(V / 128, N / 128), 256, 0, stream>>>(pred_bf, decw_bf, decb, out, N, V, D);
}

// Round 2
// 1605.160 us; speedup vs baseline: 1.0548x; 1.0548x over previous
//
#include <hip/hip_runtime.h>
#include <stdint.h>

typedef unsigned short u16;
typedef __bf16 bf16x8 __attribute__((ext_vector_type(8)));
typedef float f32x4 __attribute__((ext_vector_type(4)));

#define AS1 __attribute__((address_space(1)))
#define AS3 __attribute__((address_space(3)))

// Problem constants
static constexpr int S = 512, Bb = 8, D = 1024, V = 32000, L = 6, NH = 16, HD = 64;
static constexpr int N = S * Bb;        // 4096 token rows
static constexpr int D3 = 3 * D;        // 3072

__device__ __forceinline__ u16 f2bf(float f) {
  union { float f; uint32_t u; } c; c.f = f;
  uint32_t r = c.u + 0x7FFFu + ((c.u >> 16) & 1u);
  return (u16)(r >> 16);
}

__device__ __forceinline__ void gload16(const void* g, void* l) {
  __builtin_amdgcn_global_load_lds((const AS1 void*)g, (AS3 void*)l, 16, 0, 0);
}

// ---------------- generic f32 -> bf16 convert (vectorized) ----------------
__global__ __launch_bounds__(256) void cvt_kernel(const float* __restrict__ in,
                                                  u16* __restrict__ out, int n4) {
  int idx = blockIdx.x * 256 + threadIdx.x;
  if (idx < n4) {
    float4 v = ((const float4*)in)[idx];
    ushort4 o;
    o.x = f2bf(v.x); o.y = f2bf(v.y); o.z = f2bf(v.z); o.w = f2bf(v.w);
    ((ushort4*)out)[idx] = o;
  }
}

// ---------------- embed_mean transpose + convert (1024x1024) ----------------
__global__ __launch_bounds__(256) void transpose_cvt(const float* __restrict__ in,
                                                     u16* __restrict__ out) {
  __shared__ float t[32][33];
  const int bx = blockIdx.x * 32, by = blockIdx.y * 32;
  const int tid = threadIdx.x;
  const int c = tid & 31;
#pragma unroll
  for (int r = tid >> 5; r < 32; r += 8)
    t[r][c] = in[(size_t)(by + r) * D + bx + c];
  __syncthreads();
#pragma unroll
  for (int r = tid >> 5; r < 32; r += 8)
    out[(size_t)(bx + r) * D + by + c] = f2bf(t[c][r]);
}

// ---------------- embedding gather * sqrt(D) -> bf16 ----------------
__global__ __launch_bounds__(256) void gather_kernel(const int* __restrict__ src,
                                                     const float* __restrict__ emb,
                                                     u16* __restrict__ xe) {
  int idx = blockIdx.x * 256 + threadIdx.x;        // one thread = 4 elems
  int n = idx >> 8, d4 = (idx & 255) * 4;
  int tok = src[n];
  float4 v = *(const float4*)(emb + (size_t)tok * D + d4);
  ushort4 o;
  o.x = f2bf(v.x * 32.f); o.y = f2bf(v.y * 32.f);
  o.z = f2bf(v.z * 32.f); o.w = f2bf(v.w * 32.f);
  *(ushort4*)(xe + (size_t)n * D + d4) = o;
}

// ---------------- add sinusoidal PE; produce f32 master + bf16 copy ----------------
__global__ __launch_bounds__(256) void pe_kernel(const float* __restrict__ t,
                                                 float* __restrict__ x,
                                                 u16* __restrict__ xb) {
  int idx = blockIdx.x * 256 + threadIdx.x;        // over N*D
  int d = idx & (D - 1);
  int s = idx >> 13;                               // n = idx>>10, s = n>>3
  float freq = __expf(-(float)(d & ~1) * (9.210340371976184f / 1024.f));
  float a = (float)s * freq;
  float p = (d & 1) ? __cosf(a) : __sinf(a);
  float v = t[idx] + p;
  x[idx] = v;
  xb[idx] = f2bf(v);
}

// ---------------- fused residual-add + LayerNorm; f32 master + bf16 copy ----------------
__global__ __launch_bounds__(256) void ln_kernel(const float* __restrict__ xold,
                                                 const float* __restrict__ delta,
                                                 const float* __restrict__ g,
                                                 const float* __restrict__ bb,
                                                 float* __restrict__ xnew,
                                                 u16* __restrict__ xbf) {
  const int row = blockIdx.x * 4 + (threadIdx.x >> 6);
  const int lane = threadIdx.x & 63;
  const float* xr = xold + (size_t)row * D;
  const float* dr = delta + (size_t)row * D;
  float v[16];
  float s = 0.f;
#pragma unroll
  for (int j = 0; j < 16; ++j) { v[j] = xr[j * 64 + lane] + dr[j * 64 + lane]; s += v[j]; }
  for (int off = 32; off; off >>= 1) s += __shfl_xor(s, off);
  float mu = s * (1.f / 1024.f);
  float s2 = 0.f;
#pragma unroll
  for (int j = 0; j < 16; ++j) { float dd = v[j] - mu; s2 += dd * dd; }
  for (int off = 32; off; off >>= 1) s2 += __shfl_xor(s2, off);
  float rstd = rsqrtf(s2 * (1.f / 1024.f) + 1e-5f);
#pragma unroll
  for (int j = 0; j < 16; ++j) {
    int c = j * 64 + lane;
    float y = (v[j] - mu) * rstd * g[c] + bb[c];
    xnew[(size_t)row * D + c] = y;
    xbf[(size_t)row * D + c] = f2bf(y);
  }
}

// ---------------- V transpose per (b,h): vtg[bh][d][s] = V[s][d] ----------------
__global__ __launch_bounds__(256) void vtrans_kernel(const u16* __restrict__ qkv,
                                                     u16* __restrict__ vtg) {
  __shared__ u16 t[64][72];
  const int st = blockIdx.x * 64;
  const int bh = blockIdx.y;
  const int b = bh >> 4, h = bh & 15;
  const int tid = threadIdx.x;
#pragma unroll
  for (int r = 0; r < 4; ++r) {
    int l = r * 1024 + tid * 4;
    int s = l >> 6, d = l & 63;
    ushort4 v = *(const ushort4*)(qkv + (size_t)((st + s) * Bb + b) * D3 + 2 * D + h * HD + d);
    *(ushort4*)&t[s][d] = v;
  }
  __syncthreads();
  u16* o = vtg + (size_t)bh * (HD * S) + st;
#pragma unroll
  for (int r = 0; r < 4; ++r) {
    int l = r * 1024 + tid * 4;
    int d = l >> 6, s = l & 63;
    ushort4 v;
    v.x = t[s][d]; v.y = t[s + 1][d]; v.z = t[s + 2][d]; v.w = t[s + 3][d];
    *(ushort4*)(o + (size_t)d * S + s) = v;
  }
}

// ---------------- GEMM 128x128 (m97 structure) for DxD shapes ----------------
template <int EPI, bool OBF>   // EPI: 0 none, 1 bias, 2 bias+relu. OBF: bf16 out else f32.
__global__ __launch_bounds__(256, 2) void gemm_bt(const u16* __restrict__ A,
                                                  const u16* __restrict__ B,
                                                  const float* __restrict__ bias,
                                                  void* __restrict__ Cout,
                                                  int Nr, int M, int K) {
  __shared__ u16 lA[8192];
  __shared__ u16 lB[8192];
  const int tid = threadIdx.x;
  const int lane = tid & 63;
  const int w = tid >> 6;
  const int wm = w >> 1, wn = w & 1;
  const int l15 = lane & 15, l4 = lane >> 4;
  const int row0 = blockIdx.y * 128, col0 = blockIdx.x * 128;

  const int sfl = tid * 8;
  const int srow = sfl >> 6;
  const int scol = sfl & 63;
  const u16* Ag = A + (size_t)(row0 + srow) * K + scol;
  const u16* Bg = B + (size_t)(col0 + srow) * K + scol;

  f32x4 acc[4][4] = {};

  for (int kt = 0; kt < K; kt += 64) {
#pragma unroll
    for (int r = 0; r < 4; ++r) {
      gload16(Ag + (size_t)r * 32 * K + kt, &lA[r * 2048 + sfl]);
      gload16(Bg + (size_t)r * 32 * K + kt, &lB[r * 2048 + sfl]);
    }
    asm volatile("s_waitcnt vmcnt(0)" ::: "memory");
    __syncthreads();
#pragma unroll
    for (int kk = 0; kk < 2; ++kk) {
      bf16x8 af[4], bfr[4];
#pragma unroll
      for (int i = 0; i < 4; ++i)
        af[i] = *(const bf16x8*)&lA[(wm * 64 + i * 16 + l15) * 64 + kk * 32 + l4 * 8];
#pragma unroll
      for (int i = 0; i < 4; ++i)
        bfr[i] = *(const bf16x8*)&lB[(wn * 64 + i * 16 + l15) * 64 + kk * 32 + l4 * 8];
#pragma unroll
      for (int i = 0; i < 4; ++i)
#pragma unroll
        for (int j = 0; j < 4; ++j)
          acc[i][j] = __builtin_amdgcn_mfma_f32_16x16x32_bf16(af[i], bfr[j], acc[i][j], 0, 0, 0);
    }
    __syncthreads();
  }

#pragma unroll
  for (int i = 0; i < 4; ++i) {
    const int rb = row0 + wm * 64 + i * 16 + l4 * 4;
#pragma unroll
    for (int j = 0; j < 4; ++j) {
      const int c = col0 + wn * 64 + j * 16 + l15;
      float bv = 0.f;
      if constexpr (EPI >= 1) bv = bias[c];
#pragma unroll
      for (int q = 0; q < 4; ++q) {
        float v = acc[i][j][q] + bv;
        if constexpr (EPI == 2) v = fmaxf(v, 0.f);
        size_t o = (size_t)(rb + q) * M + c;
        if constexpr (OBF) ((u16*)Cout)[o] = f2bf(v);
        else ((float*)Cout)[o] = v;
      }
    }
  }
}

// ================= 256x256 8-phase GEMM (guide template, T1+T2+T3+T4+T5) =================
// C[N,M] = A[N,K] @ B[M,K]^T (+bias). 512 threads = 8 waves (2M x 4N), BK=64.
// LDS: 2 buffers x (A[256][64] + B[256][64]) bf16 = 128 KB.
// Quadrant halves: Aq0 = rows {0-63,128-191}, Aq1 = {64-127,192-255} (first read p0/p2)
//                  Bq0 = cols {0-31,64-95,128-159,192-223}, Bq1 = rest (first read p0/p1)
// Stage rotation: p0: Aq1(t+1) -> other buf; p1/p2/p3: Aq0/Bq0/Bq1(t+2) -> current buf
// (each region is re-staged >=1 barrier after its last LDS read).
// vmcnt(6) at each K-tile boundary = 3 half-tiles (2 loads each) in flight.
// Slot swizzle (involution): LDS[row][s] holds global[row][s ^ (row&7)], s = 16B slot.

__device__ __forceinline__ void stageA256(const u16* __restrict__ A, u16* __restrict__ ldsA,
                                          int q, int row0, int K, int kt, int w, int lane) {
  const int ls = lane & 7, lr = lane >> 3;
  const int gs = (ls ^ lr) * 8;
#pragma unroll
  for (int i = 0; i < 2; ++i) {
    int rb = q * 8 + w + i * 16;
    int row = rb * 8 + lr;
    gload16(A + (size_t)(row0 + row) * K + kt + gs, ldsA + row * 64 + ls * 8);
  }
}

__device__ __forceinline__ void stageB256(const u16* __restrict__ B, u16* __restrict__ ldsB,
                                          int q, int col0, int K, int kt, int w, int lane) {
  const int ls = lane & 7, lr = lane >> 3;
  const int gs = (ls ^ lr) * 8;
#pragma unroll
  for (int i = 0; i < 2; ++i) {
    int cb = q * 4 + (w & 3) + (w >> 2) * 8 + i * 16;
    int col = cb * 8 + lr;
    gload16(B + (size_t)(col0 + col) * K + kt + gs, ldsB + col * 64 + ls * 8);
  }
}

template <int EPI, bool OBF>
__global__ __launch_bounds__(512, 2) void gemm256(const u16* __restrict__ A,
                                                  const u16* __restrict__ B,
                                                  const float* __restrict__ bias,
                                                  void* __restrict__ Cout,
                                                  int M, int K) {
  __shared__ u16 lds[65536];          // 128 KB
  const int tid = threadIdx.x;
  const int w = tid >> 6, lane = tid & 63;
  const int wm = w >> 2, wn = w & 3;
  const int l15 = lane & 15, l4 = lane >> 4;

  // block mapping: XCD swizzle (nwg%8==0 guaranteed by launch) + 8-row supergroup
  const int nwg = gridDim.x;
  const int cpx = nwg >> 3;
  const int f = blockIdx.x;
  const int swz = (f & 7) * cpx + (f >> 3);
  const int GX = M >> 8;
  const int per = 8 * GX;
  const int g = swz / per, r = swz % per;
  const int by = g * 8 + (r & 7);
  const int bx = r >> 3;
  const int row0 = by * 256, col0 = bx * 256;

  const int NT = K >> 6;

  f32x4 acc[8][4] = {};
  bf16x8 af[4][2], b0[2][2], b1[2][2];

  // read-side swizzled byte-slot base (elements): ((ks*4+l4) ^ (l15&7)) * 8
  const int sw0 = ((0 * 4 + l4) ^ (l15 & 7)) * 8;
  const int sw1 = ((1 * 4 + l4) ^ (l15 & 7)) * 8;

  // ---------------- prologue: tile0 (4 halves) + tile1 (3 halves) ----------------
  {
    u16* A0 = lds;             u16* B0l = lds + 16384;
    u16* A1 = lds + 32768;     u16* B1l = lds + 49152;
    stageA256(A, A0, 0, row0, K, 0, w, lane);
    stageB256(B, B0l, 0, col0, K, 0, w, lane);
    stageB256(B, B0l, 1, col0, K, 0, w, lane);
    stageA256(A, A0, 1, row0, K, 0, w, lane);
    if (NT > 1) {
      stageA256(A, A1, 0, row0, K, 64, w, lane);
      stageB256(B, B1l, 0, col0, K, 64, w, lane);
      stageB256(B, B1l, 1, col0, K, 64, w, lane);
      asm volatile("s_waitcnt vmcnt(6)" ::: "memory");
    } else {
      asm volatile("s_waitcnt vmcnt(0)" ::: "memory");
    }
    __builtin_amdgcn_s_barrier();
  }

  for (int t = 0; t < NT; ++t) {
    const int cur = t & 1;
    u16* LA = lds + cur * 32768;
    u16* LB = LA + 16384;
    u16* LAn = lds + (cur ^ 1) * 32768;

    // ======== phase 0: quadrant (mh=0, nh=0) — 12 ds_reads ========
#pragma unroll
    for (int mf = 0; mf < 4; ++mf) {
      int row = wm * 128 + mf * 16 + l15;
      af[mf][0] = *(const bf16x8*)&LA[row * 64 + sw0];
      af[mf][1] = *(const bf16x8*)&LA[row * 64 + sw1];
    }
#pragma unroll
    for (int nf = 0; nf < 2; ++nf) {
      int col = wn * 64 + nf * 16 + l15;
      b0[nf][0] = *(const bf16x8*)&LB[col * 64 + sw0];
      b0[nf][1] = *(const bf16x8*)&LB[col * 64 + sw1];
    }
    if (t + 1 < NT) stageA256(A, LAn, 1, row0, K, (t + 1) * 64, w, lane);   // Aq1(t+1)
    asm volatile("s_waitcnt lgkmcnt(8)" ::: "memory");
    __builtin_amdgcn_s_barrier();
    asm volatile("s_waitcnt lgkmcnt(0)" ::: "memory");
    __builtin_amdgcn_sched_barrier(0);
    __builtin_amdgcn_s_setprio(1);
#pragma unroll
    for (int mf = 0; mf < 4; ++mf)
#pragma unroll
      for (int nf = 0; nf < 2; ++nf)
#pragma unroll
        for (int ks = 0; ks < 2; ++ks)
          acc[mf][nf] = __builtin_amdgcn_mfma_f32_16x16x32_bf16(af[mf][ks], b0[nf][ks], acc[mf][nf], 0, 0, 0);
    __builtin_amdgcn_s_setprio(0);
    __builtin_amdgcn_s_barrier();

    // ======== phase 1: quadrant (0,1) — 4 ds_reads ========
#pragma unroll
    for (int nf = 0; nf < 2; ++nf) {
      int col = wn * 64 + 32 + nf * 16 + l15;
      b1[nf][0] = *(const bf16x8*)&LB[col * 64 + sw0];
      b1[nf][1] = *(const bf16x8*)&LB[col * 64 + sw1];
    }
    if (t + 2 < NT) stageA256(A, LA, 0, row0, K, (t + 2) * 64, w, lane);    // Aq0(t+2)
    __builtin_amdgcn_s_barrier();
    asm volatile("s_waitcnt lgkmcnt(0)" ::: "memory");
    __builtin_amdgcn_sched_barrier(0);
    __builtin_amdgcn_s_setprio(1);
#pragma unroll
    for (int mf = 0; mf < 4; ++mf)
#pragma unroll
      for (int nf = 0; nf < 2; ++nf)
#pragma unroll
        for (int ks = 0; ks < 2; ++ks)
          acc[mf][2 + nf] = __builtin_amdgcn_mfma_f32_16x16x32_bf16(af[mf][ks], b1[nf][ks], acc[mf][2 + nf], 0, 0, 0);
    __builtin_amdgcn_s_setprio(0);
    __builtin_amdgcn_s_barrier();

    // ======== phase 2: quadrant (1,0) — 8 ds_reads ========
#pragma unroll
    for (int mf = 0; mf < 4; ++mf) {
      int row = wm * 128 + 64 + mf * 16 + l15;
      af[mf][0] = *(const bf16x8*)&LA[row * 64 + sw0];
      af[mf][1] = *(const bf16x8*)&LA[row * 64 + sw1];
    }
    if (t + 2 < NT) stageB256(B, LB, 0, col0, K, (t + 2) * 64, w, lane);    // Bq0(t+2)
    __builtin_amdgcn_s_barrier();
    asm volatile("s_waitcnt lgkmcnt(0)" ::: "memory");
    __builtin_amdgcn_sched_barrier(0);
    __builtin_amdgcn_s_setprio(1);
#pragma unroll
    for (int mf = 0; mf < 4; ++mf)
#pragma unroll
      for (int nf = 0; nf < 2; ++nf)
#pragma unroll
        for (int ks = 0; ks < 2; ++ks)
          acc[4 + mf][nf] = __builtin_amdgcn_mfma_f32_16x16x32_bf16(af[mf][ks], b0[nf][ks], acc[4 + mf][nf], 0, 0, 0);
    __builtin_amdgcn_s_setprio(0);
    __builtin_amdgcn_s_barrier();

    // ======== phase 3: quadrant (1,1) — 0 ds_reads, K-tile boundary vmcnt ========
    if (t + 2 < NT) stageB256(B, LB, 1, col0, K, (t + 2) * 64, w, lane);    // Bq1(t+2)
    if (t < NT - 2) asm volatile("s_waitcnt vmcnt(6)" ::: "memory");
    else            asm volatile("s_waitcnt vmcnt(0)" ::: "memory");
    __builtin_amdgcn_s_barrier();
    __builtin_amdgcn_s_setprio(1);
#pragma unroll
    for (int mf = 0; mf < 4; ++mf)
#pragma unroll
      for (int nf = 0; nf < 2; ++nf)
#pragma unroll
        for (int ks = 0; ks < 2; ++ks)
          acc[4 + mf][2 + nf] = __builtin_amdgcn_mfma_f32_16x16x32_bf16(af[mf][ks], b1[nf][ks], acc[4 + mf][2 + nf], 0, 0, 0);
    __builtin_amdgcn_s_setprio(0);
    __builtin_amdgcn_s_barrier();
  }

  // ---------------- epilogue ----------------
#pragma unroll
  for (int mf = 0; mf < 8; ++mf) {
    const int rb = row0 + wm * 128 + mf * 16 + l4 * 4;
#pragma unroll
    for (int nf = 0; nf < 4; ++nf) {
      const int c = col0 + wn * 64 + nf * 16 + l15;
      float bv = 0.f;
      if constexpr (EPI >= 1) bv = bias[c];
#pragma unroll
      for (int q = 0; q < 4; ++q) {
        float v = acc[mf][nf][q] + bv;
        size_t o = (size_t)(rb + q) * M + c;
        if constexpr (OBF) ((u16*)Cout)[o] = f2bf(v);
        else ((float*)Cout)[o] = v;
      }
    }
  }
}

// ---------------- fused causal attention, one WG per (qtile, h, b) ----------------
__global__ __launch_bounds__(256, 1) void attn_kernel(const u16* __restrict__ qkv,
                                                      const u16* __restrict__ vtg,
                                                      u16* __restrict__ att) {
  __shared__ u16 Kl[S * HD];        // [s][d]   64 KB
  __shared__ u16 Vt[HD * S];        // [d][s]   64 KB
  __shared__ u16 Pl[4][32 * 64];    // per-wave P scratch, 16 KB
  const int tid = threadIdx.x, lane = tid & 63, w = tid >> 6;
  const int qt = blockIdx.x, h = blockIdx.y, b = blockIdx.z;
  const int l15 = lane & 15, l4 = lane >> 4;

  {
    const int sfl = tid * 8;
#pragma unroll
    for (int r = 0; r < 16; ++r) {
      int l = r * 2048 + sfl;
      int s = l >> 6, d = l & 63;
      gload16(qkv + (size_t)(s * Bb + b) * D3 + D + h * HD + d, &Kl[l]);
    }
    const u16* vg = vtg + (size_t)(b * NH + h) * (HD * S);
#pragma unroll
    for (int r = 0; r < 16; ++r) {
      int l = r * 2048 + sfl;
      gload16(vg + l, &Vt[l]);
    }
  }
  asm volatile("s_waitcnt vmcnt(0)" ::: "memory");
  __syncthreads();

  const int qbase = qt * 128 + w * 32;
  bf16x8 qf[2][2];
#pragma unroll
  for (int fm = 0; fm < 2; ++fm)
#pragma unroll
    for (int kk = 0; kk < 2; ++kk) {
      int qs = qbase + fm * 16 + l15;
      qf[fm][kk] = *(const bf16x8*)(qkv + (size_t)(qs * Bb + b) * D3 + h * HD + kk * 32 + l4 * 8);
    }

  float m_run[2][4], l_run[2][4];
  f32x4 o[2][4] = {};
#pragma unroll
  for (int fm = 0; fm < 2; ++fm)
#pragma unroll
    for (int j = 0; j < 4; ++j) { m_run[fm][j] = -1e30f; l_run[fm][j] = 0.f; }

  const int nchunk = (qbase + 31) / 64 + 1;
  for (int ch = 0; ch < nchunk; ++ch) {
    f32x4 sc[2][4] = {};
#pragma unroll
    for (int kk = 0; kk < 2; ++kk) {
      bf16x8 kb[4];
#pragma unroll
      for (int fn = 0; fn < 4; ++fn)
        kb[fn] = *(const bf16x8*)&Kl[(ch * 64 + fn * 16 + l15) * 64 + kk * 32 + l4 * 8];
#pragma unroll
      for (int fm = 0; fm < 2; ++fm)
#pragma unroll
        for (int fn = 0; fn < 4; ++fn)
          sc[fm][fn] = __builtin_amdgcn_mfma_f32_16x16x32_bf16(qf[fm][kk], kb[fn], sc[fm][fn], 0, 0, 0);
    }
    float pv[2][4][4], rm[2][4];
#pragma unroll
    for (int fm = 0; fm < 2; ++fm)
#pragma unroll
      for (int j = 0; j < 4; ++j) {
        float mx = -1e30f;
        int q_s = qbase + fm * 16 + l4 * 4 + j;
#pragma unroll
        for (int fn = 0; fn < 4; ++fn) {
          int k_s = ch * 64 + fn * 16 + l15;
          float vv = sc[fm][fn][j] * 0.125f;
          vv = (k_s <= q_s) ? vv : -1e30f;
          pv[fm][fn][j] = vv;
          mx = fmaxf(mx, vv);
        }
        rm[fm][j] = mx;
      }
    for (int off = 1; off <= 8; off <<= 1)
#pragma unroll
      for (int fm = 0; fm < 2; ++fm)
#pragma unroll
        for (int j = 0; j < 4; ++j)
          rm[fm][j] = fmaxf(rm[fm][j], __shfl_xor(rm[fm][j], off));
    float corr[2][4];
#pragma unroll
    for (int fm = 0; fm < 2; ++fm)
#pragma unroll
      for (int j = 0; j < 4; ++j) {
        float mn = fmaxf(m_run[fm][j], rm[fm][j]);
        corr[fm][j] = __expf(m_run[fm][j] - mn);
        m_run[fm][j] = mn;
      }
    float rs[2][4];
#pragma unroll
    for (int fm = 0; fm < 2; ++fm)
#pragma unroll
      for (int j = 0; j < 4; ++j) {
        float sum = 0.f;
#pragma unroll
        for (int fn = 0; fn < 4; ++fn) {
          float p = __expf(pv[fm][fn][j] - m_run[fm][j]);
          pv[fm][fn][j] = p;
          sum += p;
        }
        rs[fm][j] = sum;
      }
    for (int off = 1; off <= 8; off <<= 1)
#pragma unroll
      for (int fm = 0; fm < 2; ++fm)
#pragma unroll
        for (int j = 0; j < 4; ++j)
          rs[fm][j] += __shfl_xor(rs[fm][j], off);
#pragma unroll
    for (int fm = 0; fm < 2; ++fm)
#pragma unroll
      for (int j = 0; j < 4; ++j)
        l_run[fm][j] = l_run[fm][j] * corr[fm][j] + rs[fm][j];
#pragma unroll
    for (int fm = 0; fm < 2; ++fm)
#pragma unroll
      for (int fd = 0; fd < 4; ++fd)
#pragma unroll
        for (int j = 0; j < 4; ++j) o[fm][fd][j] *= corr[fm][j];
    u16* P = &Pl[w][0];
#pragma unroll
    for (int fm = 0; fm < 2; ++fm)
#pragma unroll
      for (int fn = 0; fn < 4; ++fn)
#pragma unroll
        for (int j = 0; j < 4; ++j)
          P[(fm * 16 + l4 * 4 + j) * 64 + fn * 16 + l15] = f2bf(pv[fm][fn][j]);
    asm volatile("" ::: "memory");
#pragma unroll
    for (int kk = 0; kk < 2; ++kk) {
      bf16x8 pa[2];
#pragma unroll
      for (int fm = 0; fm < 2; ++fm)
        pa[fm] = *(const bf16x8*)&P[(fm * 16 + l15) * 64 + kk * 32 + l4 * 8];
#pragma unroll
      for (int fd = 0; fd < 4; ++fd) {
        bf16x8 vb = *(const bf16x8*)&Vt[(fd * 16 + l15) * S + ch * 64 + kk * 32 + l4 * 8];
#pragma unroll
        for (int fm = 0; fm < 2; ++fm)
          o[fm][fd] = __builtin_amdgcn_mfma_f32_16x16x32_bf16(pa[fm], vb, o[fm][fd], 0, 0, 0);
      }
    }
    asm volatile("" ::: "memory");
  }
#pragma unroll
  for (int fm = 0; fm < 2; ++fm)
#pragma unroll
    for (int fd = 0; fd < 4; ++fd)
#pragma unroll
      for (int j = 0; j < 4; ++j) {
        int s = qbase + fm * 16 + l4 * 4 + j;
        int d = h * HD + fd * 16 + l15;
        att[(size_t)(s * Bb + b) * D + d] = f2bf(o[fm][fd][j] / l_run[fm][j]);
      }
}

extern "C" void kernel_launch(void* const* d_in, const int* in_sizes, int n_in,
                              void* d_out, int out_size, void* d_ws, size_t ws_size,
                              hipStream_t stream) {
  const int* src = (const int*)d_in[0];
  const float* emb = (const float*)d_in[1];
  const float* em = (const float*)d_in[2];
  const float* qkvw = (const float*)d_in[3];
  const float* qkvb = (const float*)d_in[4];
  const float* ow = (const float*)d_in[5];
  const float* ob = (const float*)d_in[6];
  const float* w1 = (const float*)d_in[7];
  const float* b1 = (const float*)d_in[8];
  const float* w2 = (const float*)d_in[9];
  const float* b2 = (const float*)d_in[10];
  const float* ln1g = (const float*)d_in[11];
  const float* ln1b = (const float*)d_in[12];
  const float* ln2g = (const float*)d_in[13];
  const float* ln2b = (const float*)d_in[14];
  const float* decw = (const float*)d_in[15];
  const float* decb = (const float*)d_in[16];
  float* out = (float*)d_out;

  uint8_t* ws = (uint8_t*)d_ws;
  size_t off = 0;
  auto alloc = [&](size_t bytes) -> void* {
    void* p = ws + off;
    off += (bytes + 255) & ~(size_t)255;
    return p;
  };
  u16* decw_bf = (u16*)alloc((size_t)V * D * 2);
  u16* lw_qkv  = (u16*)alloc((size_t)D3 * D * 2);
  u16* lw_o    = (u16*)alloc((size_t)D * D * 2);
  u16* lw_1    = (u16*)alloc((size_t)D * D * 2);
  u16* lw_2    = (u16*)alloc((size_t)D * D * 2);
  u16* em_bf   = (u16*)alloc((size_t)D * D * 2);
  u16* emT_bf  = (u16*)alloc((size_t)D * D * 2);
  u16* xe_bf   = (u16*)alloc((size_t)N * D * 2);
  float* x_f   = (float*)alloc((size_t)N * D * 4);
  u16* x_bf    = (u16*)alloc((size_t)N * D * 2);
  float* tmp_f = (float*)alloc((size_t)N * D * 4);
  u16* qkv_bf  = (u16*)alloc((size_t)N * D3 * 2);
  u16* vtg     = (u16*)alloc((size_t)N * D * 2);
  u16* att_bf  = (u16*)alloc((size_t)N * D * 2);
  u16* h_bf    = (u16*)alloc((size_t)N * D * 2);
  u16* pred_bf = (u16*)alloc((size_t)N * D * 2);
  (void)ws_size; (void)in_sizes; (void)n_in; (void)out_size;

  cvt_kernel<<<1024, 256, 0, stream>>>(em, em_bf, D * D / 4);
  transpose_cvt<<<dim3(32, 32), 256, 0, stream>>>(em, emT_bf);
  gather_kernel<<<N * D / 1024, 256, 0, stream>>>(src, emb, xe_bf);
  gemm_bt<0, false><<<dim3(D / 128, N / 128), 256, 0, stream>>>(xe_bf, em_bf, nullptr, tmp_f, N, D, D);
  pe_kernel<<<N * D / 256, 256, 0, stream>>>(tmp_f, x_f, x_bf);

  for (int l = 0; l < L; ++l) {
    cvt_kernel<<<D3 * D / 1024, 256, 0, stream>>>(qkvw + (size_t)l * D3 * D, lw_qkv, D3 * D / 4);
    cvt_kernel<<<D * D / 1024, 256, 0, stream>>>(ow + (size_t)l * D * D, lw_o, D * D / 4);
    cvt_kernel<<<D * D / 1024, 256, 0, stream>>>(w1 + (size_t)l * D * D, lw_1, D * D / 4);
    cvt_kernel<<<D * D / 1024, 256, 0, stream>>>(w2 + (size_t)l * D * D, lw_2, D * D / 4);

    gemm256<1, true><<<(D3 / 256) * (N / 256), 512, 0, stream>>>(x_bf, lw_qkv, qkvb + l * D3, qkv_bf, D3, D);
    vtrans_kernel<<<dim3(S / 64, Bb * NH), 256, 0, stream>>>(qkv_bf, vtg);
    attn_kernel<<<dim3(S / 128, NH, Bb), 256, 0, stream>>>(qkv_bf, vtg, att_bf);
    gemm_bt<1, false><<<dim3(D / 128, N / 128), 256, 0, stream>>>(att_bf, lw_o, ob + l * D, tmp_f, N, D, D);
    ln_kernel<<<N / 4, 256, 0, stream>>>(x_f, tmp_f, ln1g + l * D, ln1b + l * D, x_f, x_bf);
    gemm_bt<2, true><<<dim3(D / 128, N / 128), 256, 0, stream>>>(x_bf, lw_1, b1 + l * D, h_bf, N, D, D);
    gemm_bt<1, false><<<dim3(D / 128, N / 128), 256, 0, stream>>>(h_bf, lw_2, b2 + l * D, tmp_f, N, D, D);
    ln_kernel<<<N / 4, 256, 0, stream>>>(x_f, tmp_f, ln2g + l * D, ln2b + l * D, x_f, x_bf);
  }

  gemm_bt<0, true><<<dim3(D / 128, N / 128), 256, 0, stream>>>(x_bf, emT_bf, nullptr, pred_bf, N, D, D);
  cvt_kernel<<<(size_t)V * D / 1024, 256, 0, stream>>>(decw, decw_bf, V * D / 4);
  gemm256<1, false><<<(V / 256) * (N / 256), 512, 0, stream>>>(pred_bf, decw_bf, decb, out, V, D);
}

// Round 3
// 1570.693 us; speedup vs baseline: 1.0779x; 1.0219x over previous
//
#include <hip/hip_runtime.h>
#include <stdint.h>

typedef unsigned short u16;
typedef __bf16 bf16x8 __attribute__((ext_vector_type(8)));
typedef float f32x4 __attribute__((ext_vector_type(4)));

#define AS1 __attribute__((address_space(1)))
#define AS3 __attribute__((address_space(3)))

// Problem constants
static constexpr int S = 512, Bb = 8, D = 1024, V = 32000, L = 6, NH = 16, HD = 64;
static constexpr int N = S * Bb;        // 4096 token rows
static constexpr int D3 = 3 * D;        // 3072

__device__ __forceinline__ u16 f2bf(float f) {
  union { float f; uint32_t u; } c; c.f = f;
  uint32_t r = c.u + 0x7FFFu + ((c.u >> 16) & 1u);
  return (u16)(r >> 16);
}

__device__ __forceinline__ void gload16(const void* g, void* l) {
  __builtin_amdgcn_global_load_lds((const AS1 void*)g, (AS3 void*)l, 16, 0, 0);
}

// ---------------- generic f32 -> bf16 convert (vectorized) ----------------
__global__ __launch_bounds__(256) void cvt_kernel(const float* __restrict__ in,
                                                  u16* __restrict__ out, int n4) {
  int idx = blockIdx.x * 256 + threadIdx.x;
  if (idx < n4) {
    float4 v = ((const float4*)in)[idx];
    ushort4 o;
    o.x = f2bf(v.x); o.y = f2bf(v.y); o.z = f2bf(v.z); o.w = f2bf(v.w);
    ((ushort4*)out)[idx] = o;
  }
}

// ---------------- 4-segment convert (per-layer weight batch) ----------------
__global__ __launch_bounds__(256) void cvt4_kernel(const float* __restrict__ s0, const float* __restrict__ s1,
                                                   const float* __restrict__ s2, const float* __restrict__ s3,
                                                   u16* __restrict__ d0, u16* __restrict__ d1,
                                                   u16* __restrict__ d2, u16* __restrict__ d3,
                                                   int n0, int n1, int n2) {
  int j = blockIdx.x * 256 + threadIdx.x;
  const float* s; u16* d;
  if (j < n0) { s = s0; d = d0; }
  else {
    j -= n0;
    if (j < n1) { s = s1; d = d1; }
    else {
      j -= n1;
      if (j < n2) { s = s2; d = d2; }
      else { j -= n2; s = s3; d = d3; }
    }
  }
  float4 v = ((const float4*)s)[j];
  ushort4 o;
  o.x = f2bf(v.x); o.y = f2bf(v.y); o.z = f2bf(v.z); o.w = f2bf(v.w);
  ((ushort4*)d)[j] = o;
}

// ---------------- embed_mean transpose + convert (1024x1024) ----------------
__global__ __launch_bounds__(256) void transpose_cvt(const float* __restrict__ in,
                                                     u16* __restrict__ out) {
  __shared__ float t[32][33];
  const int bx = blockIdx.x * 32, by = blockIdx.y * 32;
  const int tid = threadIdx.x;
  const int c = tid & 31;
#pragma unroll
  for (int r = tid >> 5; r < 32; r += 8)
    t[r][c] = in[(size_t)(by + r) * D + bx + c];
  __syncthreads();
#pragma unroll
  for (int r = tid >> 5; r < 32; r += 8)
    out[(size_t)(bx + r) * D + by + c] = f2bf(t[c][r]);
}

// ---------------- embedding gather * sqrt(D) -> bf16 ----------------
__global__ __launch_bounds__(256) void gather_kernel(const int* __restrict__ src,
                                                     const float* __restrict__ emb,
                                                     u16* __restrict__ xe) {
  int idx = blockIdx.x * 256 + threadIdx.x;        // one thread = 4 elems
  int n = idx >> 8, d4 = (idx & 255) * 4;
  int tok = src[n];
  float4 v = *(const float4*)(emb + (size_t)tok * D + d4);
  ushort4 o;
  o.x = f2bf(v.x * 32.f); o.y = f2bf(v.y * 32.f);
  o.z = f2bf(v.z * 32.f); o.w = f2bf(v.w * 32.f);
  *(ushort4*)(xe + (size_t)n * D + d4) = o;
}

// ---------------- add sinusoidal PE; produce f32 master + bf16 copy ----------------
__global__ __launch_bounds__(256) void pe_kernel(const float* __restrict__ t,
                                                 float* __restrict__ x,
                                                 u16* __restrict__ xb) {
  int idx = blockIdx.x * 256 + threadIdx.x;        // over N*D
  int d = idx & (D - 1);
  int s = idx >> 13;                               // n = idx>>10, s = n>>3
  float freq = __expf(-(float)(d & ~1) * (9.210340371976184f / 1024.f));
  float a = (float)s * freq;
  float p = (d & 1) ? __cosf(a) : __sinf(a);
  float v = t[idx] + p;
  x[idx] = v;
  xb[idx] = f2bf(v);
}

// ---------------- fused residual-add + LayerNorm; f32 master + bf16 copy ----------------
__global__ __launch_bounds__(256) void ln_kernel(const float* __restrict__ xold,
                                                 const float* __restrict__ delta,
                                                 const float* __restrict__ g,
                                                 const float* __restrict__ bb,
                                                 float* __restrict__ xnew,
                                                 u16* __restrict__ xbf) {
  const int row = blockIdx.x * 4 + (threadIdx.x >> 6);
  const int lane = threadIdx.x & 63;
  const float* xr = xold + (size_t)row * D;
  const float* dr = delta + (size_t)row * D;
  float v[16];
  float s = 0.f;
#pragma unroll
  for (int j = 0; j < 16; ++j) { v[j] = xr[j * 64 + lane] + dr[j * 64 + lane]; s += v[j]; }
  for (int off = 32; off; off >>= 1) s += __shfl_xor(s, off);
  float mu = s * (1.f / 1024.f);
  float s2 = 0.f;
#pragma unroll
  for (int j = 0; j < 16; ++j) { float dd = v[j] - mu; s2 += dd * dd; }
  for (int off = 32; off; off >>= 1) s2 += __shfl_xor(s2, off);
  float rstd = rsqrtf(s2 * (1.f / 1024.f) + 1e-5f);
#pragma unroll
  for (int j = 0; j < 16; ++j) {
    int c = j * 64 + lane;
    float y = (v[j] - mu) * rstd * g[c] + bb[c];
    xnew[(size_t)row * D + c] = y;
    xbf[(size_t)row * D + c] = f2bf(y);
  }
}

// ---------------- V transpose per (b,h): vtg[bh][d][s] = V[s][d] ----------------
__global__ __launch_bounds__(256) void vtrans_kernel(const u16* __restrict__ qkv,
                                                     u16* __restrict__ vtg) {
  __shared__ u16 t[64][72];
  const int st = blockIdx.x * 64;
  const int bh = blockIdx.y;
  const int b = bh >> 4, h = bh & 15;
  const int tid = threadIdx.x;
#pragma unroll
  for (int r = 0; r < 4; ++r) {
    int l = r * 1024 + tid * 4;
    int s = l >> 6, d = l & 63;
    ushort4 v = *(const ushort4*)(qkv + (size_t)((st + s) * Bb + b) * D3 + 2 * D + h * HD + d);
    *(ushort4*)&t[s][d] = v;
  }
  __syncthreads();
  u16* o = vtg + (size_t)bh * (HD * S) + st;
#pragma unroll
  for (int r = 0; r < 4; ++r) {
    int l = r * 1024 + tid * 4;
    int d = l >> 6, s = l & 63;
    ushort4 v;
    v.x = t[s][d]; v.y = t[s + 1][d]; v.z = t[s + 2][d]; v.w = t[s + 3][d];
    *(ushort4*)(o + (size_t)d * S + s) = v;
  }
}

// ---------------- GEMM 128x128 (m97 structure) for DxD shapes ----------------
template <int EPI, bool OBF>   // EPI: 0 none, 1 bias, 2 bias+relu. OBF: bf16 out else f32.
__global__ __launch_bounds__(256, 2) void gemm_bt(const u16* __restrict__ A,
                                                  const u16* __restrict__ B,
                                                  const float* __restrict__ bias,
                                                  void* __restrict__ Cout,
                                                  int Nr, int M, int K) {
  __shared__ u16 lA[8192];
  __shared__ u16 lB[8192];
  const int tid = threadIdx.x;
  const int lane = tid & 63;
  const int w = tid >> 6;
  const int wm = w >> 1, wn = w & 1;
  const int l15 = lane & 15, l4 = lane >> 4;
  const int row0 = blockIdx.y * 128, col0 = blockIdx.x * 128;

  const int sfl = tid * 8;
  const int srow = sfl >> 6;
  const int scol = sfl & 63;
  const u16* Ag = A + (size_t)(row0 + srow) * K + scol;
  const u16* Bg = B + (size_t)(col0 + srow) * K + scol;

  f32x4 acc[4][4] = {};

  for (int kt = 0; kt < K; kt += 64) {
#pragma unroll
    for (int r = 0; r < 4; ++r) {
      gload16(Ag + (size_t)r * 32 * K + kt, &lA[r * 2048 + sfl]);
      gload16(Bg + (size_t)r * 32 * K + kt, &lB[r * 2048 + sfl]);
    }
    asm volatile("s_waitcnt vmcnt(0)" ::: "memory");
    __syncthreads();
#pragma unroll
    for (int kk = 0; kk < 2; ++kk) {
      bf16x8 af[4], bfr[4];
#pragma unroll
      for (int i = 0; i < 4; ++i)
        af[i] = *(const bf16x8*)&lA[(wm * 64 + i * 16 + l15) * 64 + kk * 32 + l4 * 8];
#pragma unroll
      for (int i = 0; i < 4; ++i)
        bfr[i] = *(const bf16x8*)&lB[(wn * 64 + i * 16 + l15) * 64 + kk * 32 + l4 * 8];
#pragma unroll
      for (int i = 0; i < 4; ++i)
#pragma unroll
        for (int j = 0; j < 4; ++j)
          acc[i][j] = __builtin_amdgcn_mfma_f32_16x16x32_bf16(af[i], bfr[j], acc[i][j], 0, 0, 0);
    }
    __syncthreads();
  }

#pragma unroll
  for (int i = 0; i < 4; ++i) {
    const int rb = row0 + wm * 64 + i * 16 + l4 * 4;
#pragma unroll
    for (int j = 0; j < 4; ++j) {
      const int c = col0 + wn * 64 + j * 16 + l15;
      float bv = 0.f;
      if constexpr (EPI >= 1) bv = bias[c];
#pragma unroll
      for (int q = 0; q < 4; ++q) {
        float v = acc[i][j][q] + bv;
        if constexpr (EPI == 2) v = fmaxf(v, 0.f);
        size_t o = (size_t)(rb + q) * M + c;
        if constexpr (OBF) ((u16*)Cout)[o] = f2bf(v);
        else ((float*)Cout)[o] = v;
      }
    }
  }
}

// ================= 256x256 8-phase GEMM (T1+T2+T3+T4+T5) =================
// C[N,M] = A[N,K] @ B[M,K]^T (+bias). 512 threads = 8 waves (2M x 4N), BK=64.
// LDS: 2 buffers x (A[256][64] + B[256][64]) bf16 = 128 KB.
// Region last-read phases: Aq0:p0, Bq0:p0, Bq1:p1, Aq1:p2.
// Stage rotation (all into CURRENT buffer, 2 tiles ahead):
//   p1: Aq0(t+2), p2: Bq0(t+2), p3: Bq1(t+2)+Aq1(t+2).
// Boundary vmcnt(8) at end of p3 keeps exactly the 8 loads issued this tile
// (for t+2) in flight and drains all t+1 loads, the youngest of which was
// issued a FULL TILE (4 phases) earlier -> >=1300cy latency hiding per load.
// Slot swizzle (involution): LDS[row][s] holds global[row][s ^ (row&7)], s = 16B slot.

__device__ __forceinline__ void stageA256(const u16* __restrict__ A, u16* __restrict__ ldsA,
                                          int q, int row0, int K, int kt, int w, int lane) {
  const int ls = lane & 7, lr = lane >> 3;
  const int gs = (ls ^ lr) * 8;
#pragma unroll
  for (int i = 0; i < 2; ++i) {
    int rb = q * 8 + w + i * 16;
    int row = rb * 8 + lr;
    gload16(A + (size_t)(row0 + row) * K + kt + gs, ldsA + row * 64 + ls * 8);
  }
}

__device__ __forceinline__ void stageB256(const u16* __restrict__ B, u16* __restrict__ ldsB,
                                          int q, int col0, int K, int kt, int w, int lane) {
  const int ls = lane & 7, lr = lane >> 3;
  const int gs = (ls ^ lr) * 8;
#pragma unroll
  for (int i = 0; i < 2; ++i) {
    int cb = q * 4 + (w & 3) + (w >> 2) * 8 + i * 16;
    int col = cb * 8 + lr;
    gload16(B + (size_t)(col0 + col) * K + kt + gs, ldsB + col * 64 + ls * 8);
  }
}

template <int EPI, bool OBF>
__global__ __launch_bounds__(512, 2) void gemm256(const u16* __restrict__ A,
                                                  const u16* __restrict__ B,
                                                  const float* __restrict__ bias,
                                                  void* __restrict__ Cout,
                                                  int M, int K) {
  __shared__ u16 lds[65536];          // 128 KB
  const int tid = threadIdx.x;
  const int w = tid >> 6, lane = tid & 63;
  const int wm = w >> 2, wn = w & 3;
  const int l15 = lane & 15, l4 = lane >> 4;

  // block mapping: XCD swizzle (nwg%8==0 guaranteed by launch) + 8-row supergroup
  const int nwg = gridDim.x;
  const int cpx = nwg >> 3;
  const int f = blockIdx.x;
  const int swz = (f & 7) * cpx + (f >> 3);
  const int GX = M >> 8;
  const int per = 8 * GX;
  const int g = swz / per, r = swz % per;
  const int by = g * 8 + (r & 7);
  const int bx = r >> 3;
  const int row0 = by * 256, col0 = bx * 256;

  const int NT = K >> 6;

  f32x4 acc[8][4] = {};
  bf16x8 af[4][2], b0[2][2], b1[2][2];

  // read-side swizzled slot base (elements): ((ks*4+l4) ^ (l15&7)) * 8
  const int sw0 = ((0 * 4 + l4) ^ (l15 & 7)) * 8;
  const int sw1 = ((1 * 4 + l4) ^ (l15 & 7)) * 8;

  // ---------------- prologue: tile0 -> buf0, tile1 -> buf1 ----------------
  {
    u16* A0 = lds;             u16* B0l = lds + 16384;
    u16* A1 = lds + 32768;     u16* B1l = lds + 49152;
    stageA256(A, A0, 0, row0, K, 0, w, lane);
    stageB256(B, B0l, 0, col0, K, 0, w, lane);
    stageB256(B, B0l, 1, col0, K, 0, w, lane);
    stageA256(A, A0, 1, row0, K, 0, w, lane);
    if (NT > 1) {
      stageA256(A, A1, 0, row0, K, 64, w, lane);
      stageB256(B, B1l, 0, col0, K, 64, w, lane);
      stageB256(B, B1l, 1, col0, K, 64, w, lane);
      stageA256(A, A1, 1, row0, K, 64, w, lane);
      asm volatile("s_waitcnt vmcnt(8)" ::: "memory");
    } else {
      asm volatile("s_waitcnt vmcnt(0)" ::: "memory");
    }
    __builtin_amdgcn_s_barrier();
  }

  for (int t = 0; t < NT; ++t) {
    const int cur = t & 1;
    u16* LA = lds + cur * 32768;
    u16* LB = LA + 16384;
    const bool pf = (t + 2 < NT);
    const int kpf = (t + 2) * 64;

    // ======== phase 0: quadrant (0,0) — 12 ds_reads, no stage ========
#pragma unroll
    for (int mf = 0; mf < 4; ++mf) {
      int row = wm * 128 + mf * 16 + l15;
      af[mf][0] = *(const bf16x8*)&LA[row * 64 + sw0];
      af[mf][1] = *(const bf16x8*)&LA[row * 64 + sw1];
    }
#pragma unroll
    for (int nf = 0; nf < 2; ++nf) {
      int col = wn * 64 + nf * 16 + l15;
      b0[nf][0] = *(const bf16x8*)&LB[col * 64 + sw0];
      b0[nf][1] = *(const bf16x8*)&LB[col * 64 + sw1];
    }
    asm volatile("s_waitcnt lgkmcnt(8)" ::: "memory");
    __builtin_amdgcn_s_barrier();
    asm volatile("s_waitcnt lgkmcnt(0)" ::: "memory");
    __builtin_amdgcn_sched_barrier(0);
    __builtin_amdgcn_s_setprio(1);
#pragma unroll
    for (int mf = 0; mf < 4; ++mf)
#pragma unroll
      for (int nf = 0; nf < 2; ++nf)
#pragma unroll
        for (int ks = 0; ks < 2; ++ks)
          acc[mf][nf] = __builtin_amdgcn_mfma_f32_16x16x32_bf16(af[mf][ks], b0[nf][ks], acc[mf][nf], 0, 0, 0);
    __builtin_amdgcn_s_setprio(0);
    __builtin_amdgcn_s_barrier();

    // ======== phase 1: quadrant (0,1) — 4 ds_reads; stage Aq0(t+2) ========
#pragma unroll
    for (int nf = 0; nf < 2; ++nf) {
      int col = wn * 64 + 32 + nf * 16 + l15;
      b1[nf][0] = *(const bf16x8*)&LB[col * 64 + sw0];
      b1[nf][1] = *(const bf16x8*)&LB[col * 64 + sw1];
    }
    if (pf) stageA256(A, LA, 0, row0, K, kpf, w, lane);
    __builtin_amdgcn_s_barrier();
    asm volatile("s_waitcnt lgkmcnt(0)" ::: "memory");
    __builtin_amdgcn_sched_barrier(0);
    __builtin_amdgcn_s_setprio(1);
#pragma unroll
    for (int mf = 0; mf < 4; ++mf)
#pragma unroll
      for (int nf = 0; nf < 2; ++nf)
#pragma unroll
        for (int ks = 0; ks < 2; ++ks)
          acc[mf][2 + nf] = __builtin_amdgcn_mfma_f32_16x16x32_bf16(af[mf][ks], b1[nf][ks], acc[mf][2 + nf], 0, 0, 0);
    __builtin_amdgcn_s_setprio(0);
    __builtin_amdgcn_s_barrier();

    // ======== phase 2: quadrant (1,0) — 8 ds_reads; stage Bq0(t+2) ========
#pragma unroll
    for (int mf = 0; mf < 4; ++mf) {
      int row = wm * 128 + 64 + mf * 16 + l15;
      af[mf][0] = *(const bf16x8*)&LA[row * 64 + sw0];
      af[mf][1] = *(const bf16x8*)&LA[row * 64 + sw1];
    }
    if (pf) stageB256(B, LB, 0, col0, K, kpf, w, lane);
    __builtin_amdgcn_s_barrier();
    asm volatile("s_waitcnt lgkmcnt(0)" ::: "memory");
    __builtin_amdgcn_sched_barrier(0);
    __builtin_amdgcn_s_setprio(1);
#pragma unroll
    for (int mf = 0; mf < 4; ++mf)
#pragma unroll
      for (int nf = 0; nf < 2; ++nf)
#pragma unroll
        for (int ks = 0; ks < 2; ++ks)
          acc[4 + mf][nf] = __builtin_amdgcn_mfma_f32_16x16x32_bf16(af[mf][ks], b0[nf][ks], acc[4 + mf][nf], 0, 0, 0);
    __builtin_amdgcn_s_setprio(0);
    __builtin_amdgcn_s_barrier();

    // ======== phase 3: quadrant (1,1) — reg-only MFMA; stage Bq1+Aq1(t+2);
    //          boundary vmcnt AFTER the MFMA so the drain hides under compute ====
    if (pf) {
      stageB256(B, LB, 1, col0, K, kpf, w, lane);
      stageA256(A, LA, 1, row0, K, kpf, w, lane);
    }
    __builtin_amdgcn_s_setprio(1);
#pragma unroll
    for (int mf = 0; mf < 4; ++mf)
#pragma unroll
      for (int nf = 0; nf < 2; ++nf)
#pragma unroll
        for (int ks = 0; ks < 2; ++ks)
          acc[4 + mf][2 + nf] = __builtin_amdgcn_mfma_f32_16x16x32_bf16(af[mf][ks], b1[nf][ks], acc[4 + mf][2 + nf], 0, 0, 0);
    __builtin_amdgcn_s_setprio(0);
    if (pf)               asm volatile("s_waitcnt vmcnt(8)" ::: "memory");
    else if (t + 1 < NT)  asm volatile("s_waitcnt vmcnt(0)" ::: "memory");
    __builtin_amdgcn_s_barrier();
  }

  // ---------------- epilogue ----------------
#pragma unroll
  for (int mf = 0; mf < 8; ++mf) {
    const int rb = row0 + wm * 128 + mf * 16 + l4 * 4;
#pragma unroll
    for (int nf = 0; nf < 4; ++nf) {
      const int c = col0 + wn * 64 + nf * 16 + l15;
      float bv = 0.f;
      if constexpr (EPI >= 1) bv = bias[c];
#pragma unroll
      for (int q = 0; q < 4; ++q) {
        float v = acc[mf][nf][q] + bv;
        size_t o = (size_t)(rb + q) * M + c;
        if constexpr (OBF) ((u16*)Cout)[o] = f2bf(v);
        else ((float*)Cout)[o] = v;
      }
    }
  }
}

// ---------------- fused causal attention, one WG per (qtile, h, b) ----------------
__global__ __launch_bounds__(256, 1) void attn_kernel(const u16* __restrict__ qkv,
                                                      const u16* __restrict__ vtg,
                                                      u16* __restrict__ att) {
  __shared__ u16 Kl[S * HD];        // [s][d]   64 KB
  __shared__ u16 Vt[HD * S];        // [d][s]   64 KB
  __shared__ u16 Pl[4][32 * 64];    // per-wave P scratch, 16 KB
  const int tid = threadIdx.x, lane = tid & 63, w = tid >> 6;
  const int qt = blockIdx.x, h = blockIdx.y, b = blockIdx.z;
  const int l15 = lane & 15, l4 = lane >> 4;

  {
    const int sfl = tid * 8;
#pragma unroll
    for (int r = 0; r < 16; ++r) {
      int l = r * 2048 + sfl;
      int s = l >> 6, d = l & 63;
      gload16(qkv + (size_t)(s * Bb + b) * D3 + D + h * HD + d, &Kl[l]);
    }
    const u16* vg = vtg + (size_t)(b * NH + h) * (HD * S);
#pragma unroll
    for (int r = 0; r < 16; ++r) {
      int l = r * 2048 + sfl;
      gload16(vg + l, &Vt[l]);
    }
  }
  asm volatile("s_waitcnt vmcnt(0)" ::: "memory");
  __syncthreads();

  const int qbase = qt * 128 + w * 32;
  bf16x8 qf[2][2];
#pragma unroll
  for (int fm = 0; fm < 2; ++fm)
#pragma unroll
    for (int kk = 0; kk < 2; ++kk) {
      int qs = qbase + fm * 16 + l15;
      qf[fm][kk] = *(const bf16x8*)(qkv + (size_t)(qs * Bb + b) * D3 + h * HD + kk * 32 + l4 * 8);
    }

  float m_run[2][4], l_run[2][4];
  f32x4 o[2][4] = {};
#pragma unroll
  for (int fm = 0; fm < 2; ++fm)
#pragma unroll
    for (int j = 0; j < 4; ++j) { m_run[fm][j] = -1e30f; l_run[fm][j] = 0.f; }

  const int nchunk = (qbase + 31) / 64 + 1;
  for (int ch = 0; ch < nchunk; ++ch) {
    f32x4 sc[2][4] = {};
#pragma unroll
    for (int kk = 0; kk < 2; ++kk) {
      bf16x8 kb[4];
#pragma unroll
      for (int fn = 0; fn < 4; ++fn)
        kb[fn] = *(const bf16x8*)&Kl[(ch * 64 + fn * 16 + l15) * 64 + kk * 32 + l4 * 8];
#pragma unroll
      for (int fm = 0; fm < 2; ++fm)
#pragma unroll
        for (int fn = 0; fn < 4; ++fn)
          sc[fm][fn] = __builtin_amdgcn_mfma_f32_16x16x32_bf16(qf[fm][kk], kb[fn], sc[fm][fn], 0, 0, 0);
    }
    float pv[2][4][4], rm[2][4];
#pragma unroll
    for (int fm = 0; fm < 2; ++fm)
#pragma unroll
      for (int j = 0; j < 4; ++j) {
        float mx = -1e30f;
        int q_s = qbase + fm * 16 + l4 * 4 + j;
#pragma unroll
        for (int fn = 0; fn < 4; ++fn) {
          int k_s = ch * 64 + fn * 16 + l15;
          float vv = sc[fm][fn][j] * 0.125f;
          vv = (k_s <= q_s) ? vv : -1e30f;
          pv[fm][fn][j] = vv;
          mx = fmaxf(mx, vv);
        }
        rm[fm][j] = mx;
      }
    for (int off = 1; off <= 8; off <<= 1)
#pragma unroll
      for (int fm = 0; fm < 2; ++fm)
#pragma unroll
        for (int j = 0; j < 4; ++j)
          rm[fm][j] = fmaxf(rm[fm][j], __shfl_xor(rm[fm][j], off));
    float corr[2][4];
#pragma unroll
    for (int fm = 0; fm < 2; ++fm)
#pragma unroll
      for (int j = 0; j < 4; ++j) {
        float mn = fmaxf(m_run[fm][j], rm[fm][j]);
        corr[fm][j] = __expf(m_run[fm][j] - mn);
        m_run[fm][j] = mn;
      }
    float rs[2][4];
#pragma unroll
    for (int fm = 0; fm < 2; ++fm)
#pragma unroll
      for (int j = 0; j < 4; ++j) {
        float sum = 0.f;
#pragma unroll
        for (int fn = 0; fn < 4; ++fn) {
          float p = __expf(pv[fm][fn][j] - m_run[fm][j]);
          pv[fm][fn][j] = p;
          sum += p;
        }
        rs[fm][j] = sum;
      }
    for (int off = 1; off <= 8; off <<= 1)
#pragma unroll
      for (int fm = 0; fm < 2; ++fm)
#pragma unroll
        for (int j = 0; j < 4; ++j)
          rs[fm][j] += __shfl_xor(rs[fm][j], off);
#pragma unroll
    for (int fm = 0; fm < 2; ++fm)
#pragma unroll
      for (int j = 0; j < 4; ++j)
        l_run[fm][j] = l_run[fm][j] * corr[fm][j] + rs[fm][j];
#pragma unroll
    for (int fm = 0; fm < 2; ++fm)
#pragma unroll
      for (int fd = 0; fd < 4; ++fd)
#pragma unroll
        for (int j = 0; j < 4; ++j) o[fm][fd][j] *= corr[fm][j];
    u16* P = &Pl[w][0];
#pragma unroll
    for (int fm = 0; fm < 2; ++fm)
#pragma unroll
      for (int fn = 0; fn < 4; ++fn)
#pragma unroll
        for (int j = 0; j < 4; ++j)
          P[(fm * 16 + l4 * 4 + j) * 64 + fn * 16 + l15] = f2bf(pv[fm][fn][j]);
    asm volatile("" ::: "memory");
#pragma unroll
    for (int kk = 0; kk < 2; ++kk) {
      bf16x8 pa[2];
#pragma unroll
      for (int fm = 0; fm < 2; ++fm)
        pa[fm] = *(const bf16x8*)&P[(fm * 16 + l15) * 64 + kk * 32 + l4 * 8];
#pragma unroll
      for (int fd = 0; fd < 4; ++fd) {
        bf16x8 vb = *(const bf16x8*)&Vt[(fd * 16 + l15) * S + ch * 64 + kk * 32 + l4 * 8];
#pragma unroll
        for (int fm = 0; fm < 2; ++fm)
          o[fm][fd] = __builtin_amdgcn_mfma_f32_16x16x32_bf16(pa[fm], vb, o[fm][fd], 0, 0, 0);
      }
    }
    asm volatile("" ::: "memory");
  }
#pragma unroll
  for (int fm = 0; fm < 2; ++fm)
#pragma unroll
    for (int fd = 0; fd < 4; ++fd)
#pragma unroll
      for (int j = 0; j < 4; ++j) {
        int s = qbase + fm * 16 + l4 * 4 + j;
        int d = h * HD + fd * 16 + l15;
        att[(size_t)(s * Bb + b) * D + d] = f2bf(o[fm][fd][j] / l_run[fm][j]);
      }
}

extern "C" void kernel_launch(void* const* d_in, const int* in_sizes, int n_in,
                              void* d_out, int out_size, void* d_ws, size_t ws_size,
                              hipStream_t stream) {
  const int* src = (const int*)d_in[0];
  const float* emb = (const float*)d_in[1];
  const float* em = (const float*)d_in[2];
  const float* qkvw = (const float*)d_in[3];
  const float* qkvb = (const float*)d_in[4];
  const float* ow = (const float*)d_in[5];
  const float* ob = (const float*)d_in[6];
  const float* w1 = (const float*)d_in[7];
  const float* b1 = (const float*)d_in[8];
  const float* w2 = (const float*)d_in[9];
  const float* b2 = (const float*)d_in[10];
  const float* ln1g = (const float*)d_in[11];
  const float* ln1b = (const float*)d_in[12];
  const float* ln2g = (const float*)d_in[13];
  const float* ln2b = (const float*)d_in[14];
  const float* decw = (const float*)d_in[15];
  const float* decb = (const float*)d_in[16];
  float* out = (float*)d_out;

  uint8_t* ws = (uint8_t*)d_ws;
  size_t off = 0;
  auto alloc = [&](size_t bytes) -> void* {
    void* p = ws + off;
    off += (bytes + 255) & ~(size_t)255;
    return p;
  };
  u16* decw_bf = (u16*)alloc((size_t)V * D * 2);
  u16* lw_qkv  = (u16*)alloc((size_t)D3 * D * 2);
  u16* lw_o    = (u16*)alloc((size_t)D * D * 2);
  u16* lw_1    = (u16*)alloc((size_t)D * D * 2);
  u16* lw_2    = (u16*)alloc((size_t)D * D * 2);
  u16* em_bf   = (u16*)alloc((size_t)D * D * 2);
  u16* emT_bf  = (u16*)alloc((size_t)D * D * 2);
  u16* xe_bf   = (u16*)alloc((size_t)N * D * 2);
  float* x_f   = (float*)alloc((size_t)N * D * 4);
  u16* x_bf    = (u16*)alloc((size_t)N * D * 2);
  float* tmp_f = (float*)alloc((size_t)N * D * 4);
  u16* qkv_bf  = (u16*)alloc((size_t)N * D3 * 2);
  u16* vtg     = (u16*)alloc((size_t)N * D * 2);
  u16* att_bf  = (u16*)alloc((size_t)N * D * 2);
  u16* h_bf    = (u16*)alloc((size_t)N * D * 2);
  u16* pred_bf = (u16*)alloc((size_t)N * D * 2);
  (void)ws_size; (void)in_sizes; (void)n_in; (void)out_size;

  cvt_kernel<<<1024, 256, 0, stream>>>(em, em_bf, D * D / 4);
  transpose_cvt<<<dim3(32, 32), 256, 0, stream>>>(em, emT_bf);
  gather_kernel<<<N * D / 1024, 256, 0, stream>>>(src, emb, xe_bf);
  gemm_bt<0, false><<<dim3(D / 128, N / 128), 256, 0, stream>>>(xe_bf, em_bf, nullptr, tmp_f, N, D, D);
  pe_kernel<<<N * D / 256, 256, 0, stream>>>(tmp_f, x_f, x_bf);

  const int nqkv4 = D3 * D / 4;     // 786432
  const int ndd4 = D * D / 4;       // 262144
  for (int l = 0; l < L; ++l) {
    cvt4_kernel<<<(nqkv4 + 3 * ndd4) / 256, 256, 0, stream>>>(
        qkvw + (size_t)l * D3 * D, ow + (size_t)l * D * D,
        w1 + (size_t)l * D * D, w2 + (size_t)l * D * D,
        lw_qkv, lw_o, lw_1, lw_2, nqkv4, ndd4, ndd4);

    gemm256<1, true><<<(D3 / 256) * (N / 256), 512, 0, stream>>>(x_bf, lw_qkv, qkvb + l * D3, qkv_bf, D3, D);
    vtrans_kernel<<<dim3(S / 64, Bb * NH), 256, 0, stream>>>(qkv_bf, vtg);
    attn_kernel<<<dim3(S / 128, NH, Bb), 256, 0, stream>>>(qkv_bf, vtg, att_bf);
    gemm_bt<1, false><<<dim3(D / 128, N / 128), 256, 0, stream>>>(att_bf, lw_o, ob + l * D, tmp_f, N, D, D);
    ln_kernel<<<N / 4, 256, 0, stream>>>(x_f, tmp_f, ln1g + l * D, ln1b + l * D, x_f, x_bf);
    gemm_bt<2, true><<<dim3(D / 128, N / 128), 256, 0, stream>>>(x_bf, lw_1, b1 + l * D, h_bf, N, D, D);
    gemm_bt<1, false><<<dim3(D / 128, N / 128), 256, 0, stream>>>(h_bf, lw_2, b2 + l * D, tmp_f, N, D, D);
    ln_kernel<<<N / 4, 256, 0, stream>>>(x_f, tmp_f, ln2g + l * D, ln2b + l * D, x_f, x_bf);
  }

  gemm_bt<0, true><<<dim3(D / 128, N / 128), 256, 0, stream>>>(x_bf, emT_bf, nullptr, pred_bf, N, D, D);
  cvt_kernel<<<(size_t)V * D / 1024, 256, 0, stream>>>(decw, decw_bf, V * D / 4);
  gemm256<1, false><<<(V / 256) * (N / 256), 512, 0, stream>>>(pred_bf, decw_bf, decb, out, V, D);
}

// Round 4
// 1497.946 us; speedup vs baseline: 1.1303x; 1.0486x over previous
//
#include <hip/hip_runtime.h>
#include <stdint.h>

typedef unsigned short u16;
typedef __bf16 bf16x8 __attribute__((ext_vector_type(8)));
typedef float f32x4 __attribute__((ext_vector_type(4)));

#define AS1 __attribute__((address_space(1)))
#define AS3 __attribute__((address_space(3)))

// Problem constants
static constexpr int S = 512, Bb = 8, D = 1024, V = 32000, L = 6, NH = 16, HD = 64;
static constexpr int N = S * Bb;        // 4096 token rows
static constexpr int D3 = 3 * D;        // 3072

__device__ __forceinline__ u16 f2bf(float f) {
  union { float f; uint32_t u; } c; c.f = f;
  uint32_t r = c.u + 0x7FFFu + ((c.u >> 16) & 1u);
  return (u16)(r >> 16);
}

__device__ __forceinline__ void gload16(const void* g, void* l) {
  __builtin_amdgcn_global_load_lds((const AS1 void*)g, (AS3 void*)l, 16, 0, 0);
}

// ---------------- generic f32 -> bf16 convert (vectorized) ----------------
__global__ __launch_bounds__(256) void cvt_kernel(const float* __restrict__ in,
                                                  u16* __restrict__ out, int n4) {
  int idx = blockIdx.x * 256 + threadIdx.x;
  if (idx < n4) {
    float4 v = ((const float4*)in)[idx];
    ushort4 o;
    o.x = f2bf(v.x); o.y = f2bf(v.y); o.z = f2bf(v.z); o.w = f2bf(v.w);
    ((ushort4*)out)[idx] = o;
  }
}

// ---------------- 4-segment convert (per-layer weight batch) ----------------
__global__ __launch_bounds__(256) void cvt4_kernel(const float* __restrict__ s0, const float* __restrict__ s1,
                                                   const float* __restrict__ s2, const float* __restrict__ s3,
                                                   u16* __restrict__ d0, u16* __restrict__ d1,
                                                   u16* __restrict__ d2, u16* __restrict__ d3,
                                                   int n0, int n1, int n2) {
  int j = blockIdx.x * 256 + threadIdx.x;
  const float* s; u16* d;
  if (j < n0) { s = s0; d = d0; }
  else {
    j -= n0;
    if (j < n1) { s = s1; d = d1; }
    else {
      j -= n1;
      if (j < n2) { s = s2; d = d2; }
      else { j -= n2; s = s3; d = d3; }
    }
  }
  float4 v = ((const float4*)s)[j];
  ushort4 o;
  o.x = f2bf(v.x); o.y = f2bf(v.y); o.z = f2bf(v.z); o.w = f2bf(v.w);
  ((ushort4*)d)[j] = o;
}

// ---------------- embed_mean transpose + convert (1024x1024) ----------------
__global__ __launch_bounds__(256) void transpose_cvt(const float* __restrict__ in,
                                                     u16* __restrict__ out) {
  __shared__ float t[32][33];
  const int bx = blockIdx.x * 32, by = blockIdx.y * 32;
  const int tid = threadIdx.x;
  const int c = tid & 31;
#pragma unroll
  for (int r = tid >> 5; r < 32; r += 8)
    t[r][c] = in[(size_t)(by + r) * D + bx + c];
  __syncthreads();
#pragma unroll
  for (int r = tid >> 5; r < 32; r += 8)
    out[(size_t)(bx + r) * D + by + c] = f2bf(t[c][r]);
}

// ---------------- embedding gather * sqrt(D) -> bf16 ----------------
__global__ __launch_bounds__(256) void gather_kernel(const int* __restrict__ src,
                                                     const float* __restrict__ emb,
                                                     u16* __restrict__ xe) {
  int idx = blockIdx.x * 256 + threadIdx.x;        // one thread = 4 elems
  int n = idx >> 8, d4 = (idx & 255) * 4;
  int tok = src[n];
  float4 v = *(const float4*)(emb + (size_t)tok * D + d4);
  ushort4 o;
  o.x = f2bf(v.x * 32.f); o.y = f2bf(v.y * 32.f);
  o.z = f2bf(v.z * 32.f); o.w = f2bf(v.w * 32.f);
  *(ushort4*)(xe + (size_t)n * D + d4) = o;
}

// ---------------- add sinusoidal PE; produce f32 master + bf16 copy ----------------
__global__ __launch_bounds__(256) void pe_kernel(const float* __restrict__ t,
                                                 float* __restrict__ x,
                                                 u16* __restrict__ xb) {
  int idx = blockIdx.x * 256 + threadIdx.x;        // over N*D
  int d = idx & (D - 1);
  int s = idx >> 13;                               // n = idx>>10, s = n>>3
  float freq = __expf(-(float)(d & ~1) * (9.210340371976184f / 1024.f));
  float a = (float)s * freq;
  float p = (d & 1) ? __cosf(a) : __sinf(a);
  float v = t[idx] + p;
  x[idx] = v;
  xb[idx] = f2bf(v);
}

// ---------------- fused residual-add + LayerNorm; f32 master + bf16 copy ----------------
__global__ __launch_bounds__(256) void ln_kernel(const float* __restrict__ xold,
                                                 const float* __restrict__ delta,
                                                 const float* __restrict__ g,
                                                 const float* __restrict__ bb,
                                                 float* __restrict__ xnew,
                                                 u16* __restrict__ xbf) {
  const int row = blockIdx.x * 4 + (threadIdx.x >> 6);
  const int lane = threadIdx.x & 63;
  const float* xr = xold + (size_t)row * D;
  const float* dr = delta + (size_t)row * D;
  float v[16];
  float s = 0.f;
#pragma unroll
  for (int j = 0; j < 16; ++j) { v[j] = xr[j * 64 + lane] + dr[j * 64 + lane]; s += v[j]; }
  for (int off = 32; off; off >>= 1) s += __shfl_xor(s, off);
  float mu = s * (1.f / 1024.f);
  float s2 = 0.f;
#pragma unroll
  for (int j = 0; j < 16; ++j) { float dd = v[j] - mu; s2 += dd * dd; }
  for (int off = 32; off; off >>= 1) s2 += __shfl_xor(s2, off);
  float rstd = rsqrtf(s2 * (1.f / 1024.f) + 1e-5f);
#pragma unroll
  for (int j = 0; j < 16; ++j) {
    int c = j * 64 + lane;
    float y = (v[j] - mu) * rstd * g[c] + bb[c];
    xnew[(size_t)row * D + c] = y;
    xbf[(size_t)row * D + c] = f2bf(y);
  }
}

// ---------------- V transpose per (b,h): vtg[bh][d][s] = V[s][d] ----------------
__global__ __launch_bounds__(256) void vtrans_kernel(const u16* __restrict__ qkv,
                                                     u16* __restrict__ vtg) {
  __shared__ u16 t[64][72];
  const int st = blockIdx.x * 64;
  const int bh = blockIdx.y;
  const int b = bh >> 4, h = bh & 15;
  const int tid = threadIdx.x;
#pragma unroll
  for (int r = 0; r < 4; ++r) {
    int l = r * 1024 + tid * 4;
    int s = l >> 6, d = l & 63;
    ushort4 v = *(const ushort4*)(qkv + (size_t)((st + s) * Bb + b) * D3 + 2 * D + h * HD + d);
    *(ushort4*)&t[s][d] = v;
  }
  __syncthreads();
  u16* o = vtg + (size_t)bh * (HD * S) + st;
#pragma unroll
  for (int r = 0; r < 4; ++r) {
    int l = r * 1024 + tid * 4;
    int d = l >> 6, s = l & 63;
    ushort4 v;
    v.x = t[s][d]; v.y = t[s + 1][d]; v.z = t[s + 2][d]; v.w = t[s + 3][d];
    *(ushort4*)(o + (size_t)d * S + s) = v;
  }
}

// ---------------- GEMM 64x128 tile for DxD shapes: grid 512 -> 2+ blocks/CU ----------------
// C[Nr,M] = A[Nr,K] @ B[M,K]^T. BM=64, BN=128, BK=64. 4 waves: wm=row-half(32), wn=col-half(64).
// 24 KB LDS -> up to 6 blocks/CU; cross-block overlap hides the 2-barrier stalls.
template <int EPI, bool OBF>   // EPI: 0 none, 1 bias, 2 bias+relu. OBF: bf16 out else f32.
__global__ __launch_bounds__(256) void gemm64(const u16* __restrict__ A,
                                              const u16* __restrict__ B,
                                              const float* __restrict__ bias,
                                              void* __restrict__ Cout,
                                              int M, int K) {
  __shared__ u16 lA[4096];    //  64x64
  __shared__ u16 lB[8192];    // 128x64
  const int tid = threadIdx.x;
  const int lane = tid & 63;
  const int w = tid >> 6;
  const int wm = w >> 1, wn = w & 1;
  const int l15 = lane & 15, l4 = lane >> 4;
  const int row0 = blockIdx.y * 64, col0 = blockIdx.x * 128;

  const int sfl = tid * 8;
  const int srow = sfl >> 6;          // 0..31
  const int scol = sfl & 63;
  const u16* Ag = A + (size_t)(row0 + srow) * K + scol;
  const u16* Bg = B + (size_t)(col0 + srow) * K + scol;

  f32x4 acc[2][4] = {};

  for (int kt = 0; kt < K; kt += 64) {
#pragma unroll
    for (int r = 0; r < 2; ++r)
      gload16(Ag + (size_t)r * 32 * K + kt, &lA[r * 2048 + sfl]);
#pragma unroll
    for (int r = 0; r < 4; ++r)
      gload16(Bg + (size_t)r * 32 * K + kt, &lB[r * 2048 + sfl]);
    asm volatile("s_waitcnt vmcnt(0)" ::: "memory");
    __syncthreads();
#pragma unroll
    for (int kk = 0; kk < 2; ++kk) {
      bf16x8 af[2], bfr[4];
#pragma unroll
      for (int i = 0; i < 2; ++i)
        af[i] = *(const bf16x8*)&lA[(wm * 32 + i * 16 + l15) * 64 + kk * 32 + l4 * 8];
#pragma unroll
      for (int j = 0; j < 4; ++j)
        bfr[j] = *(const bf16x8*)&lB[(wn * 64 + j * 16 + l15) * 64 + kk * 32 + l4 * 8];
#pragma unroll
      for (int i = 0; i < 2; ++i)
#pragma unroll
        for (int j = 0; j < 4; ++j)
          acc[i][j] = __builtin_amdgcn_mfma_f32_16x16x32_bf16(af[i], bfr[j], acc[i][j], 0, 0, 0);
    }
    __syncthreads();
  }

#pragma unroll
  for (int i = 0; i < 2; ++i) {
    const int rb = row0 + wm * 32 + i * 16 + l4 * 4;
#pragma unroll
    for (int j = 0; j < 4; ++j) {
      const int c = col0 + wn * 64 + j * 16 + l15;
      float bv = 0.f;
      if constexpr (EPI >= 1) bv = bias[c];
#pragma unroll
      for (int q = 0; q < 4; ++q) {
        float v = acc[i][j][q] + bv;
        if constexpr (EPI == 2) v = fmaxf(v, 0.f);
        size_t o = (size_t)(rb + q) * M + c;
        if constexpr (OBF) ((u16*)Cout)[o] = f2bf(v);
        else ((float*)Cout)[o] = v;
      }
    }
  }
}

// ================= 256x256 8-phase GEMM (T1+T2+T3+T4+T5) =================
// At K=1024 this runs ~800-850 TF (matches learn_hip m248 K=1024 regime).
__device__ __forceinline__ void stageA256(const u16* __restrict__ A, u16* __restrict__ ldsA,
                                          int q, int row0, int K, int kt, int w, int lane) {
  const int ls = lane & 7, lr = lane >> 3;
  const int gs = (ls ^ lr) * 8;
#pragma unroll
  for (int i = 0; i < 2; ++i) {
    int rb = q * 8 + w + i * 16;
    int row = rb * 8 + lr;
    gload16(A + (size_t)(row0 + row) * K + kt + gs, ldsA + row * 64 + ls * 8);
  }
}

__device__ __forceinline__ void stageB256(const u16* __restrict__ B, u16* __restrict__ ldsB,
                                          int q, int col0, int K, int kt, int w, int lane) {
  const int ls = lane & 7, lr = lane >> 3;
  const int gs = (ls ^ lr) * 8;
#pragma unroll
  for (int i = 0; i < 2; ++i) {
    int cb = q * 4 + (w & 3) + (w >> 2) * 8 + i * 16;
    int col = cb * 8 + lr;
    gload16(B + (size_t)(col0 + col) * K + kt + gs, ldsB + col * 64 + ls * 8);
  }
}

template <int EPI, bool OBF>
__global__ __launch_bounds__(512, 2) void gemm256(const u16* __restrict__ A,
                                                  const u16* __restrict__ B,
                                                  const float* __restrict__ bias,
                                                  void* __restrict__ Cout,
                                                  int M, int K) {
  __shared__ u16 lds[65536];          // 128 KB
  const int tid = threadIdx.x;
  const int w = tid >> 6, lane = tid & 63;
  const int wm = w >> 2, wn = w & 3;
  const int l15 = lane & 15, l4 = lane >> 4;

  const int nwg = gridDim.x;
  const int cpx = nwg >> 3;
  const int f = blockIdx.x;
  const int swz = (f & 7) * cpx + (f >> 3);
  const int GX = M >> 8;
  const int per = 8 * GX;
  const int g = swz / per, r = swz % per;
  const int by = g * 8 + (r & 7);
  const int bx = r >> 3;
  const int row0 = by * 256, col0 = bx * 256;

  const int NT = K >> 6;

  f32x4 acc[8][4] = {};
  bf16x8 af[4][2], b0[2][2], b1[2][2];

  const int sw0 = ((0 * 4 + l4) ^ (l15 & 7)) * 8;
  const int sw1 = ((1 * 4 + l4) ^ (l15 & 7)) * 8;

  {
    u16* A0 = lds;             u16* B0l = lds + 16384;
    u16* A1 = lds + 32768;     u16* B1l = lds + 49152;
    stageA256(A, A0, 0, row0, K, 0, w, lane);
    stageB256(B, B0l, 0, col0, K, 0, w, lane);
    stageB256(B, B0l, 1, col0, K, 0, w, lane);
    stageA256(A, A0, 1, row0, K, 0, w, lane);
    if (NT > 1) {
      stageA256(A, A1, 0, row0, K, 64, w, lane);
      stageB256(B, B1l, 0, col0, K, 64, w, lane);
      stageB256(B, B1l, 1, col0, K, 64, w, lane);
      stageA256(A, A1, 1, row0, K, 64, w, lane);
      asm volatile("s_waitcnt vmcnt(8)" ::: "memory");
    } else {
      asm volatile("s_waitcnt vmcnt(0)" ::: "memory");
    }
    __builtin_amdgcn_s_barrier();
  }

  for (int t = 0; t < NT; ++t) {
    const int cur = t & 1;
    u16* LA = lds + cur * 32768;
    u16* LB = LA + 16384;
    const bool pf = (t + 2 < NT);
    const int kpf = (t + 2) * 64;

    // phase 0: quadrant (0,0)
#pragma unroll
    for (int mf = 0; mf < 4; ++mf) {
      int row = wm * 128 + mf * 16 + l15;
      af[mf][0] = *(const bf16x8*)&LA[row * 64 + sw0];
      af[mf][1] = *(const bf16x8*)&LA[row * 64 + sw1];
    }
#pragma unroll
    for (int nf = 0; nf < 2; ++nf) {
      int col = wn * 64 + nf * 16 + l15;
      b0[nf][0] = *(const bf16x8*)&LB[col * 64 + sw0];
      b0[nf][1] = *(const bf16x8*)&LB[col * 64 + sw1];
    }
    asm volatile("s_waitcnt lgkmcnt(8)" ::: "memory");
    __builtin_amdgcn_s_barrier();
    asm volatile("s_waitcnt lgkmcnt(0)" ::: "memory");
    __builtin_amdgcn_sched_barrier(0);
    __builtin_amdgcn_s_setprio(1);
#pragma unroll
    for (int mf = 0; mf < 4; ++mf)
#pragma unroll
      for (int nf = 0; nf < 2; ++nf)
#pragma unroll
        for (int ks = 0; ks < 2; ++ks)
          acc[mf][nf] = __builtin_amdgcn_mfma_f32_16x16x32_bf16(af[mf][ks], b0[nf][ks], acc[mf][nf], 0, 0, 0);
    __builtin_amdgcn_s_setprio(0);
    __builtin_amdgcn_s_barrier();

    // phase 1: quadrant (0,1); stage Aq0(t+2)
#pragma unroll
    for (int nf = 0; nf < 2; ++nf) {
      int col = wn * 64 + 32 + nf * 16 + l15;
      b1[nf][0] = *(const bf16x8*)&LB[col * 64 + sw0];
      b1[nf][1] = *(const bf16x8*)&LB[col * 64 + sw1];
    }
    if (pf) stageA256(A, LA, 0, row0, K, kpf, w, lane);
    __builtin_amdgcn_s_barrier();
    asm volatile("s_waitcnt lgkmcnt(0)" ::: "memory");
    __builtin_amdgcn_sched_barrier(0);
    __builtin_amdgcn_s_setprio(1);
#pragma unroll
    for (int mf = 0; mf < 4; ++mf)
#pragma unroll
      for (int nf = 0; nf < 2; ++nf)
#pragma unroll
        for (int ks = 0; ks < 2; ++ks)
          acc[mf][2 + nf] = __builtin_amdgcn_mfma_f32_16x16x32_bf16(af[mf][ks], b1[nf][ks], acc[mf][2 + nf], 0, 0, 0);
    __builtin_amdgcn_s_setprio(0);
    __builtin_amdgcn_s_barrier();

    // phase 2: quadrant (1,0); stage Bq0(t+2)
#pragma unroll
    for (int mf = 0; mf < 4; ++mf) {
      int row = wm * 128 + 64 + mf * 16 + l15;
      af[mf][0] = *(const bf16x8*)&LA[row * 64 + sw0];
      af[mf][1] = *(const bf16x8*)&LA[row * 64 + sw1];
    }
    if (pf) stageB256(B, LB, 0, col0, K, kpf, w, lane);
    __builtin_amdgcn_s_barrier();
    asm volatile("s_waitcnt lgkmcnt(0)" ::: "memory");
    __builtin_amdgcn_sched_barrier(0);
    __builtin_amdgcn_s_setprio(1);
#pragma unroll
    for (int mf = 0; mf < 4; ++mf)
#pragma unroll
      for (int nf = 0; nf < 2; ++nf)
#pragma unroll
        for (int ks = 0; ks < 2; ++ks)
          acc[4 + mf][nf] = __builtin_amdgcn_mfma_f32_16x16x32_bf16(af[mf][ks], b0[nf][ks], acc[4 + mf][nf], 0, 0, 0);
    __builtin_amdgcn_s_setprio(0);
    __builtin_amdgcn_s_barrier();

    // phase 3: quadrant (1,1); stage Bq1+Aq1(t+2); boundary vmcnt after MFMA
    if (pf) {
      stageB256(B, LB, 1, col0, K, kpf, w, lane);
      stageA256(A, LA, 1, row0, K, kpf, w, lane);
    }
    __builtin_amdgcn_s_setprio(1);
#pragma unroll
    for (int mf = 0; mf < 4; ++mf)
#pragma unroll
      for (int nf = 0; nf < 2; ++nf)
#pragma unroll
        for (int ks = 0; ks < 2; ++ks)
          acc[4 + mf][2 + nf] = __builtin_amdgcn_mfma_f32_16x16x32_bf16(af[mf][ks], b1[nf][ks], acc[4 + mf][2 + nf], 0, 0, 0);
    __builtin_amdgcn_s_setprio(0);
    if (pf)               asm volatile("s_waitcnt vmcnt(8)" ::: "memory");
    else if (t + 1 < NT)  asm volatile("s_waitcnt vmcnt(0)" ::: "memory");
    __builtin_amdgcn_s_barrier();
  }

#pragma unroll
  for (int mf = 0; mf < 8; ++mf) {
    const int rb = row0 + wm * 128 + mf * 16 + l4 * 4;
#pragma unroll
    for (int nf = 0; nf < 4; ++nf) {
      const int c = col0 + wn * 64 + nf * 16 + l15;
      float bv = 0.f;
      if constexpr (EPI >= 1) bv = bias[c];
#pragma unroll
      for (int q = 0; q < 4; ++q) {
        float v = acc[mf][nf][q] + bv;
        size_t o = (size_t)(rb + q) * M + c;
        if constexpr (OBF) ((u16*)Cout)[o] = f2bf(v);
        else ((float*)Cout)[o] = v;
      }
    }
  }
}

// ---------------- fused causal attention, one WG per (qtile, h, b) ----------------
__global__ __launch_bounds__(256, 1) void attn_kernel(const u16* __restrict__ qkv,
                                                      const u16* __restrict__ vtg,
                                                      u16* __restrict__ att) {
  __shared__ u16 Kl[S * HD];        // [s][d]   64 KB
  __shared__ u16 Vt[HD * S];        // [d][s]   64 KB
  __shared__ u16 Pl[4][32 * 64];    // per-wave P scratch, 16 KB
  const int tid = threadIdx.x, lane = tid & 63, w = tid >> 6;
  const int qt = blockIdx.x, h = blockIdx.y, b = blockIdx.z;
  const int l15 = lane & 15, l4 = lane >> 4;

  {
    const int sfl = tid * 8;
#pragma unroll
    for (int r = 0; r < 16; ++r) {
      int l = r * 2048 + sfl;
      int s = l >> 6, d = l & 63;
      gload16(qkv + (size_t)(s * Bb + b) * D3 + D + h * HD + d, &Kl[l]);
    }
    const u16* vg = vtg + (size_t)(b * NH + h) * (HD * S);
#pragma unroll
    for (int r = 0; r < 16; ++r) {
      int l = r * 2048 + sfl;
      gload16(vg + l, &Vt[l]);
    }
  }
  asm volatile("s_waitcnt vmcnt(0)" ::: "memory");
  __syncthreads();

  const int qbase = qt * 128 + w * 32;
  bf16x8 qf[2][2];
#pragma unroll
  for (int fm = 0; fm < 2; ++fm)
#pragma unroll
    for (int kk = 0; kk < 2; ++kk) {
      int qs = qbase + fm * 16 + l15;
      qf[fm][kk] = *(const bf16x8*)(qkv + (size_t)(qs * Bb + b) * D3 + h * HD + kk * 32 + l4 * 8);
    }

  float m_run[2][4], l_run[2][4];
  f32x4 o[2][4] = {};
#pragma unroll
  for (int fm = 0; fm < 2; ++fm)
#pragma unroll
    for (int j = 0; j < 4; ++j) { m_run[fm][j] = -1e30f; l_run[fm][j] = 0.f; }

  const int nchunk = (qbase + 31) / 64 + 1;
  for (int ch = 0; ch < nchunk; ++ch) {
    f32x4 sc[2][4] = {};
#pragma unroll
    for (int kk = 0; kk < 2; ++kk) {
      bf16x8 kb[4];
#pragma unroll
      for (int fn = 0; fn < 4; ++fn)
        kb[fn] = *(const bf16x8*)&Kl[(ch * 64 + fn * 16 + l15) * 64 + kk * 32 + l4 * 8];
#pragma unroll
      for (int fm = 0; fm < 2; ++fm)
#pragma unroll
        for (int fn = 0; fn < 4; ++fn)
          sc[fm][fn] = __builtin_amdgcn_mfma_f32_16x16x32_bf16(qf[fm][kk], kb[fn], sc[fm][fn], 0, 0, 0);
    }
    float pv[2][4][4], rm[2][4];
#pragma unroll
    for (int fm = 0; fm < 2; ++fm)
#pragma unroll
      for (int j = 0; j < 4; ++j) {
        float mx = -1e30f;
        int q_s = qbase + fm * 16 + l4 * 4 + j;
#pragma unroll
        for (int fn = 0; fn < 4; ++fn) {
          int k_s = ch * 64 + fn * 16 + l15;
          float vv = sc[fm][fn][j] * 0.125f;
          vv = (k_s <= q_s) ? vv : -1e30f;
          pv[fm][fn][j] = vv;
          mx = fmaxf(mx, vv);
        }
        rm[fm][j] = mx;
      }
    for (int off = 1; off <= 8; off <<= 1)
#pragma unroll
      for (int fm = 0; fm < 2; ++fm)
#pragma unroll
        for (int j = 0; j < 4; ++j)
          rm[fm][j] = fmaxf(rm[fm][j], __shfl_xor(rm[fm][j], off));
    float corr[2][4];
#pragma unroll
    for (int fm = 0; fm < 2; ++fm)
#pragma unroll
      for (int j = 0; j < 4; ++j) {
        float mn = fmaxf(m_run[fm][j], rm[fm][j]);
        corr[fm][j] = __expf(m_run[fm][j] - mn);
        m_run[fm][j] = mn;
      }
    float rs[2][4];
#pragma unroll
    for (int fm = 0; fm < 2; ++fm)
#pragma unroll
      for (int j = 0; j < 4; ++j) {
        float sum = 0.f;
#pragma unroll
        for (int fn = 0; fn < 4; ++fn) {
          float p = __expf(pv[fm][fn][j] - m_run[fm][j]);
          pv[fm][fn][j] = p;
          sum += p;
        }
        rs[fm][j] = sum;
      }
    for (int off = 1; off <= 8; off <<= 1)
#pragma unroll
      for (int fm = 0; fm < 2; ++fm)
#pragma unroll
        for (int j = 0; j < 4; ++j)
          rs[fm][j] += __shfl_xor(rs[fm][j], off);
#pragma unroll
    for (int fm = 0; fm < 2; ++fm)
#pragma unroll
      for (int j = 0; j < 4; ++j)
        l_run[fm][j] = l_run[fm][j] * corr[fm][j] + rs[fm][j];
#pragma unroll
    for (int fm = 0; fm < 2; ++fm)
#pragma unroll
      for (int fd = 0; fd < 4; ++fd)
#pragma unroll
        for (int j = 0; j < 4; ++j) o[fm][fd][j] *= corr[fm][j];
    u16* P = &Pl[w][0];
#pragma unroll
    for (int fm = 0; fm < 2; ++fm)
#pragma unroll
      for (int fn = 0; fn < 4; ++fn)
#pragma unroll
        for (int j = 0; j < 4; ++j)
          P[(fm * 16 + l4 * 4 + j) * 64 + fn * 16 + l15] = f2bf(pv[fm][fn][j]);
    asm volatile("" ::: "memory");
#pragma unroll
    for (int kk = 0; kk < 2; ++kk) {
      bf16x8 pa[2];
#pragma unroll
      for (int fm = 0; fm < 2; ++fm)
        pa[fm] = *(const bf16x8*)&P[(fm * 16 + l15) * 64 + kk * 32 + l4 * 8];
#pragma unroll
      for (int fd = 0; fd < 4; ++fd) {
        bf16x8 vb = *(const bf16x8*)&Vt[(fd * 16 + l15) * S + ch * 64 + kk * 32 + l4 * 8];
#pragma unroll
        for (int fm = 0; fm < 2; ++fm)
          o[fm][fd] = __builtin_amdgcn_mfma_f32_16x16x32_bf16(pa[fm], vb, o[fm][fd], 0, 0, 0);
      }
    }
    asm volatile("" ::: "memory");
  }
#pragma unroll
  for (int fm = 0; fm < 2; ++fm)
#pragma unroll
    for (int fd = 0; fd < 4; ++fd)
#pragma unroll
      for (int j = 0; j < 4; ++j) {
        int s = qbase + fm * 16 + l4 * 4 + j;
        int d = h * HD + fd * 16 + l15;
        att[(size_t)(s * Bb + b) * D + d] = f2bf(o[fm][fd][j] / l_run[fm][j]);
      }
}

extern "C" void kernel_launch(void* const* d_in, const int* in_sizes, int n_in,
                              void* d_out, int out_size, void* d_ws, size_t ws_size,
                              hipStream_t stream) {
  const int* src = (const int*)d_in[0];
  const float* emb = (const float*)d_in[1];
  const float* em = (const float*)d_in[2];
  const float* qkvw = (const float*)d_in[3];
  const float* qkvb = (const float*)d_in[4];
  const float* ow = (const float*)d_in[5];
  const float* ob = (const float*)d_in[6];
  const float* w1 = (const float*)d_in[7];
  const float* b1 = (const float*)d_in[8];
  const float* w2 = (const float*)d_in[9];
  const float* b2 = (const float*)d_in[10];
  const float* ln1g = (const float*)d_in[11];
  const float* ln1b = (const float*)d_in[12];
  const float* ln2g = (const float*)d_in[13];
  const float* ln2b = (const float*)d_in[14];
  const float* decw = (const float*)d_in[15];
  const float* decb = (const float*)d_in[16];
  float* out = (float*)d_out;

  uint8_t* ws = (uint8_t*)d_ws;
  size_t off = 0;
  auto alloc = [&](size_t bytes) -> void* {
    void* p = ws + off;
    off += (bytes + 255) & ~(size_t)255;
    return p;
  };
  u16* decw_bf = (u16*)alloc((size_t)V * D * 2);
  u16* lw_qkv  = (u16*)alloc((size_t)D3 * D * 2);
  u16* lw_o    = (u16*)alloc((size_t)D * D * 2);
  u16* lw_1    = (u16*)alloc((size_t)D * D * 2);
  u16* lw_2    = (u16*)alloc((size_t)D * D * 2);
  u16* em_bf   = (u16*)alloc((size_t)D * D * 2);
  u16* emT_bf  = (u16*)alloc((size_t)D * D * 2);
  u16* xe_bf   = (u16*)alloc((size_t)N * D * 2);
  float* x_f   = (float*)alloc((size_t)N * D * 4);
  u16* x_bf    = (u16*)alloc((size_t)N * D * 2);
  float* tmp_f = (float*)alloc((size_t)N * D * 4);
  u16* qkv_bf  = (u16*)alloc((size_t)N * D3 * 2);
  u16* vtg     = (u16*)alloc((size_t)N * D * 2);
  u16* att_bf  = (u16*)alloc((size_t)N * D * 2);
  u16* h_bf    = (u16*)alloc((size_t)N * D * 2);
  u16* pred_bf = (u16*)alloc((size_t)N * D * 2);
  (void)ws_size; (void)in_sizes; (void)n_in; (void)out_size;

  cvt_kernel<<<1024, 256, 0, stream>>>(em, em_bf, D * D / 4);
  transpose_cvt<<<dim3(32, 32), 256, 0, stream>>>(em, emT_bf);
  gather_kernel<<<N * D / 1024, 256, 0, stream>>>(src, emb, xe_bf);
  gemm64<0, false><<<dim3(D / 128, N / 64), 256, 0, stream>>>(xe_bf, em_bf, nullptr, tmp_f, D, D);
  pe_kernel<<<N * D / 256, 256, 0, stream>>>(tmp_f, x_f, x_bf);

  const int nqkv4 = D3 * D / 4;
  const int ndd4 = D * D / 4;
  for (int l = 0; l < L; ++l) {
    cvt4_kernel<<<(nqkv4 + 3 * ndd4) / 256, 256, 0, stream>>>(
        qkvw + (size_t)l * D3 * D, ow + (size_t)l * D * D,
        w1 + (size_t)l * D * D, w2 + (size_t)l * D * D,
        lw_qkv, lw_o, lw_1, lw_2, nqkv4, ndd4, ndd4);

    gemm256<1, true><<<(D3 / 256) * (N / 256), 512, 0, stream>>>(x_bf, lw_qkv, qkvb + l * D3, qkv_bf, D3, D);
    vtrans_kernel<<<dim3(S / 64, Bb * NH), 256, 0, stream>>>(qkv_bf, vtg);
    attn_kernel<<<dim3(S / 128, NH, Bb), 256, 0, stream>>>(qkv_bf, vtg, att_bf);
    gemm64<1, false><<<dim3(D / 128, N / 64), 256, 0, stream>>>(att_bf, lw_o, ob + l * D, tmp_f, D, D);
    ln_kernel<<<N / 4, 256, 0, stream>>>(x_f, tmp_f, ln1g + l * D, ln1b + l * D, x_f, x_bf);
    gemm64<2, true><<<dim3(D / 128, N / 64), 256, 0, stream>>>(x_bf, lw_1, b1 + l * D, h_bf, D, D);
    gemm64<1, false><<<dim3(D / 128, N / 64), 256, 0, stream>>>(h_bf, lw_2, b2 + l * D, tmp_f, D, D);
    ln_kernel<<<N / 4, 256, 0, stream>>>(x_f, tmp_f, ln2g + l * D, ln2b + l * D, x_f, x_bf);
  }

  gemm64<0, true><<<dim3(D / 128, N / 64), 256, 0, stream>>>(x_bf, emT_bf, nullptr, pred_bf, D, D);
  cvt_kernel<<<(size_t)V * D / 1024, 256, 0, stream>>>(decw, decw_bf, V * D / 4);
  gemm256<1, false><<<(V / 256) * (N / 256), 512, 0, stream>>>(pred_bf, decw_bf, decb, out, V, D);
}

// Round 6
// 1357.586 us; speedup vs baseline: 1.2471x; 1.1034x over previous
//
#include <hip/hip_runtime.h>
#include <stdint.h>

typedef unsigned short u16;
typedef __bf16 bf16x8 __attribute__((ext_vector_type(8)));
typedef float f32x4 __attribute__((ext_vector_type(4)));

#define AS1 __attribute__((address_space(1)))
#define AS3 __attribute__((address_space(3)))

// Problem constants
static constexpr int S = 512, Bb = 8, D = 1024, V = 32000, L = 6, NH = 16, HD = 64;
static constexpr int N = S * Bb;        // 4096 token rows
static constexpr int D3 = 3 * D;        // 3072

__device__ __forceinline__ u16 f2bf(float f) {
  union { float f; uint32_t u; } c; c.f = f;
  uint32_t r = c.u + 0x7FFFu + ((c.u >> 16) & 1u);
  return (u16)(r >> 16);
}

__device__ __forceinline__ float bf2f(u16 u) {
  union { uint32_t i; float f; } c; c.i = ((uint32_t)u) << 16; return c.f;
}

__device__ __forceinline__ void gload16(const void* g, void* l) {
  __builtin_amdgcn_global_load_lds((const AS1 void*)g, (AS3 void*)l, 16, 0, 0);
}

// ---------------- generic f32 -> bf16 convert (vectorized) ----------------
__global__ __launch_bounds__(256) void cvt_kernel(const float* __restrict__ in,
                                                  u16* __restrict__ out, int n4) {
  int idx = blockIdx.x * 256 + threadIdx.x;
  if (idx < n4) {
    float4 v = ((const float4*)in)[idx];
    ushort4 o;
    o.x = f2bf(v.x); o.y = f2bf(v.y); o.z = f2bf(v.z); o.w = f2bf(v.w);
    ((ushort4*)out)[idx] = o;
  }
}

// ---------------- 4-segment convert (per-layer weight batch) ----------------
__global__ __launch_bounds__(256) void cvt4_kernel(const float* __restrict__ s0, const float* __restrict__ s1,
                                                   const float* __restrict__ s2, const float* __restrict__ s3,
                                                   u16* __restrict__ d0, u16* __restrict__ d1,
                                                   u16* __restrict__ d2, u16* __restrict__ d3,
                                                   int n0, int n1, int n2) {
  int j = blockIdx.x * 256 + threadIdx.x;
  const float* s; u16* d;
  if (j < n0) { s = s0; d = d0; }
  else {
    j -= n0;
    if (j < n1) { s = s1; d = d1; }
    else {
      j -= n1;
      if (j < n2) { s = s2; d = d2; }
      else { j -= n2; s = s3; d = d3; }
    }
  }
  float4 v = ((const float4*)s)[j];
  ushort4 o;
  o.x = f2bf(v.x); o.y = f2bf(v.y); o.z = f2bf(v.z); o.w = f2bf(v.w);
  ((ushort4*)d)[j] = o;
}

// ---------------- embed_mean transpose + convert (1024x1024) ----------------
__global__ __launch_bounds__(256) void transpose_cvt(const float* __restrict__ in,
                                                     u16* __restrict__ out) {
  __shared__ float t[32][33];
  const int bx = blockIdx.x * 32, by = blockIdx.y * 32;
  const int tid = threadIdx.x;
  const int c = tid & 31;
#pragma unroll
  for (int r = tid >> 5; r < 32; r += 8)
    t[r][c] = in[(size_t)(by + r) * D + bx + c];
  __syncthreads();
#pragma unroll
  for (int r = tid >> 5; r < 32; r += 8)
    out[(size_t)(bx + r) * D + by + c] = f2bf(t[c][r]);
}

// ---------------- embedding gather * sqrt(D) -> bf16 ----------------
__global__ __launch_bounds__(256) void gather_kernel(const int* __restrict__ src,
                                                     const float* __restrict__ emb,
                                                     u16* __restrict__ xe) {
  int idx = blockIdx.x * 256 + threadIdx.x;        // one thread = 4 elems
  int n = idx >> 8, d4 = (idx & 255) * 4;
  int tok = src[n];
  float4 v = *(const float4*)(emb + (size_t)tok * D + d4);
  ushort4 o;
  o.x = f2bf(v.x * 32.f); o.y = f2bf(v.y * 32.f);
  o.z = f2bf(v.z * 32.f); o.w = f2bf(v.w * 32.f);
  *(ushort4*)(xe + (size_t)n * D + d4) = o;
}

// ---------------- fused residual-add + LayerNorm (bf16 delta); f32 master + bf16 copy ----------------
__global__ __launch_bounds__(256) void ln_kernel(const float* __restrict__ xold,
                                                 const u16* __restrict__ delta,
                                                 const float* __restrict__ g,
                                                 const float* __restrict__ bb,
                                                 float* __restrict__ xnew,
                                                 u16* __restrict__ xbf) {
  const int row = blockIdx.x * 4 + (threadIdx.x >> 6);
  const int lane = threadIdx.x & 63;
  const float* xr = xold + (size_t)row * D;
  const u16* dr = delta + (size_t)row * D;
  float v[16];
  float s = 0.f;
#pragma unroll
  for (int j = 0; j < 16; ++j) { v[j] = xr[j * 64 + lane] + bf2f(dr[j * 64 + lane]); s += v[j]; }
  for (int off = 32; off; off >>= 1) s += __shfl_xor(s, off);
  float mu = s * (1.f / 1024.f);
  float s2 = 0.f;
#pragma unroll
  for (int j = 0; j < 16; ++j) { float dd = v[j] - mu; s2 += dd * dd; }
  for (int off = 32; off; off >>= 1) s2 += __shfl_xor(s2, off);
  float rstd = rsqrtf(s2 * (1.f / 1024.f) + 1e-5f);
#pragma unroll
  for (int j = 0; j < 16; ++j) {
    int c = j * 64 + lane;
    float y = (v[j] - mu) * rstd * g[c] + bb[c];
    xnew[(size_t)row * D + c] = y;
    xbf[(size_t)row * D + c] = f2bf(y);
  }
}

// ---------------- V transpose per (b,h): vtg[bh][d][s] = V[s][d] ----------------
__global__ __launch_bounds__(256) void vtrans_kernel(const u16* __restrict__ qkv,
                                                     u16* __restrict__ vtg) {
  __shared__ u16 t[64][72];
  const int st = blockIdx.x * 64;
  const int bh = blockIdx.y;
  const int b = bh >> 4, h = bh & 15;
  const int tid = threadIdx.x;
#pragma unroll
  for (int r = 0; r < 4; ++r) {
    int l = r * 1024 + tid * 4;
    int s = l >> 6, d = l & 63;
    ushort4 v = *(const ushort4*)(qkv + (size_t)((st + s) * Bb + b) * D3 + 2 * D + h * HD + d);
    *(ushort4*)&t[s][d] = v;
  }
  __syncthreads();
  u16* o = vtg + (size_t)bh * (HD * S) + st;
#pragma unroll
  for (int r = 0; r < 4; ++r) {
    int l = r * 1024 + tid * 4;
    int d = l >> 6, s = l & 63;
    ushort4 v;
    v.x = t[s][d]; v.y = t[s + 1][d]; v.z = t[s + 2][d]; v.w = t[s + 3][d];
    *(ushort4*)(o + (size_t)d * S + s) = v;
  }
}

// ---------------- GEMM 64x128 tile for DxD shapes ----------------
// EPI: 0 none, 1 bias, 2 bias+relu, 3 = +sinusoidal-PE dual write (f32 Cout + bf16 Cout2).
template <int EPI, bool OBF>
__global__ __launch_bounds__(256) void gemm64(const u16* __restrict__ A,
                                              const u16* __restrict__ B,
                                              const float* __restrict__ bias,
                                              void* __restrict__ Cout,
                                              void* __restrict__ Cout2,
                                              int M, int K) {
  __shared__ u16 lA[4096];    //  64x64
  __shared__ u16 lB[8192];    // 128x64
  const int tid = threadIdx.x;
  const int lane = tid & 63;
  const int w = tid >> 6;
  const int wm = w >> 1, wn = w & 1;
  const int l15 = lane & 15, l4 = lane >> 4;
  const int row0 = blockIdx.y * 64, col0 = blockIdx.x * 128;

  const int sfl = tid * 8;
  const int srow = sfl >> 6;          // 0..31
  const int scol = sfl & 63;
  const u16* Ag = A + (size_t)(row0 + srow) * K + scol;
  const u16* Bg = B + (size_t)(col0 + srow) * K + scol;

  f32x4 acc[2][4] = {};

  for (int kt = 0; kt < K; kt += 64) {
#pragma unroll
    for (int r = 0; r < 2; ++r)
      gload16(Ag + (size_t)r * 32 * K + kt, &lA[r * 2048 + sfl]);
#pragma unroll
    for (int r = 0; r < 4; ++r)
      gload16(Bg + (size_t)r * 32 * K + kt, &lB[r * 2048 + sfl]);
    asm volatile("s_waitcnt vmcnt(0)" ::: "memory");
    __syncthreads();
#pragma unroll
    for (int kk = 0; kk < 2; ++kk) {
      bf16x8 af[2], bfr[4];
#pragma unroll
      for (int i = 0; i < 2; ++i)
        af[i] = *(const bf16x8*)&lA[(wm * 32 + i * 16 + l15) * 64 + kk * 32 + l4 * 8];
#pragma unroll
      for (int j = 0; j < 4; ++j)
        bfr[j] = *(const bf16x8*)&lB[(wn * 64 + j * 16 + l15) * 64 + kk * 32 + l4 * 8];
#pragma unroll
      for (int i = 0; i < 2; ++i)
#pragma unroll
        for (int j = 0; j < 4; ++j)
          acc[i][j] = __builtin_amdgcn_mfma_f32_16x16x32_bf16(af[i], bfr[j], acc[i][j], 0, 0, 0);
    }
    __syncthreads();
  }

#pragma unroll
  for (int i = 0; i < 2; ++i) {
    const int rb = row0 + wm * 32 + i * 16 + l4 * 4;
#pragma unroll
    for (int j = 0; j < 4; ++j) {
      const int c = col0 + wn * 64 + j * 16 + l15;
      float bv = 0.f;
      if constexpr (EPI == 1 || EPI == 2) bv = bias[c];
      float freq = 0.f;
      if constexpr (EPI == 3)
        freq = __expf(-(float)(c & ~1) * (9.210340371976184f / 1024.f));
#pragma unroll
      for (int q = 0; q < 4; ++q) {
        float v = acc[i][j][q] + bv;
        if constexpr (EPI == 2) v = fmaxf(v, 0.f);
        size_t o = (size_t)(rb + q) * M + c;
        if constexpr (EPI == 3) {
          int s = (rb + q) >> 3;
          float a = (float)s * freq;
          float p = (c & 1) ? __cosf(a) : __sinf(a);
          v += p;
          ((float*)Cout)[o] = v;
          ((u16*)Cout2)[o] = f2bf(v);
        } else if constexpr (OBF) {
          ((u16*)Cout)[o] = f2bf(v);
        } else {
          ((float*)Cout)[o] = v;
        }
      }
    }
  }
}

// ================= 256x256 8-phase GEMM (T1+T2+T3+T4+T5) =================
__device__ __forceinline__ void stageA256(const u16* __restrict__ A, u16* __restrict__ ldsA,
                                          int q, int row0, int K, int kt, int w, int lane) {
  const int ls = lane & 7, lr = lane >> 3;
  const int gs = (ls ^ lr) * 8;
#pragma unroll
  for (int i = 0; i < 2; ++i) {
    int rb = q * 8 + w + i * 16;
    int row = rb * 8 + lr;
    gload16(A + (size_t)(row0 + row) * K + kt + gs, ldsA + row * 64 + ls * 8);
  }
}

__device__ __forceinline__ void stageB256(const u16* __restrict__ B, u16* __restrict__ ldsB,
                                          int q, int col0, int K, int kt, int w, int lane) {
  const int ls = lane & 7, lr = lane >> 3;
  const int gs = (ls ^ lr) * 8;
#pragma unroll
  for (int i = 0; i < 2; ++i) {
    int cb = q * 4 + (w & 3) + (w >> 2) * 8 + i * 16;
    int col = cb * 8 + lr;
    gload16(B + (size_t)(col0 + col) * K + kt + gs, ldsB + col * 64 + ls * 8);
  }
}

template <int EPI, bool OBF>
__global__ __launch_bounds__(512, 2) void gemm256(const u16* __restrict__ A,
                                                  const u16* __restrict__ B,
                                                  const float* __restrict__ bias,
                                                  void* __restrict__ Cout,
                                                  int M, int K) {
  __shared__ u16 lds[65536];          // 128 KB
  const int tid = threadIdx.x;
  const int w = tid >> 6, lane = tid & 63;
  const int wm = w >> 2, wn = w & 3;
  const int l15 = lane & 15, l4 = lane >> 4;

  const int nwg = gridDim.x;
  const int cpx = nwg >> 3;
  const int f = blockIdx.x;
  const int swz = (f & 7) * cpx + (f >> 3);
  const int GX = M >> 8;
  const int per = 8 * GX;
  const int g = swz / per, r = swz % per;
  const int by = g * 8 + (r & 7);
  const int bx = r >> 3;
  const int row0 = by * 256, col0 = bx * 256;

  const int NT = K >> 6;

  f32x4 acc[8][4] = {};
  bf16x8 af[4][2], b0[2][2], b1[2][2];

  const int sw0 = ((0 * 4 + l4) ^ (l15 & 7)) * 8;
  const int sw1 = ((1 * 4 + l4) ^ (l15 & 7)) * 8;

  {
    u16* A0 = lds;             u16* B0l = lds + 16384;
    u16* A1 = lds + 32768;     u16* B1l = lds + 49152;
    stageA256(A, A0, 0, row0, K, 0, w, lane);
    stageB256(B, B0l, 0, col0, K, 0, w, lane);
    stageB256(B, B0l, 1, col0, K, 0, w, lane);
    stageA256(A, A0, 1, row0, K, 0, w, lane);
    if (NT > 1) {
      stageA256(A, A1, 0, row0, K, 64, w, lane);
      stageB256(B, B1l, 0, col0, K, 64, w, lane);
      stageB256(B, B1l, 1, col0, K, 64, w, lane);
      stageA256(A, A1, 1, row0, K, 64, w, lane);
      asm volatile("s_waitcnt vmcnt(8)" ::: "memory");
    } else {
      asm volatile("s_waitcnt vmcnt(0)" ::: "memory");
    }
    __builtin_amdgcn_s_barrier();
  }

  for (int t = 0; t < NT; ++t) {
    const int cur = t & 1;
    u16* LA = lds + cur * 32768;
    u16* LB = LA + 16384;
    const bool pf = (t + 2 < NT);
    const int kpf = (t + 2) * 64;

    // phase 0: quadrant (0,0)
#pragma unroll
    for (int mf = 0; mf < 4; ++mf) {
      int row = wm * 128 + mf * 16 + l15;
      af[mf][0] = *(const bf16x8*)&LA[row * 64 + sw0];
      af[mf][1] = *(const bf16x8*)&LA[row * 64 + sw1];
    }
#pragma unroll
    for (int nf = 0; nf < 2; ++nf) {
      int col = wn * 64 + nf * 16 + l15;
      b0[nf][0] = *(const bf16x8*)&LB[col * 64 + sw0];
      b0[nf][1] = *(const bf16x8*)&LB[col * 64 + sw1];
    }
    asm volatile("s_waitcnt lgkmcnt(8)" ::: "memory");
    __builtin_amdgcn_s_barrier();
    asm volatile("s_waitcnt lgkmcnt(0)" ::: "memory");
    __builtin_amdgcn_sched_barrier(0);
    __builtin_amdgcn_s_setprio(1);
#pragma unroll
    for (int mf = 0; mf < 4; ++mf)
#pragma unroll
      for (int nf = 0; nf < 2; ++nf)
#pragma unroll
        for (int ks = 0; ks < 2; ++ks)
          acc[mf][nf] = __builtin_amdgcn_mfma_f32_16x16x32_bf16(af[mf][ks], b0[nf][ks], acc[mf][nf], 0, 0, 0);
    __builtin_amdgcn_s_setprio(0);
    __builtin_amdgcn_s_barrier();

    // phase 1: quadrant (0,1); stage Aq0(t+2)
#pragma unroll
    for (int nf = 0; nf < 2; ++nf) {
      int col = wn * 64 + 32 + nf * 16 + l15;
      b1[nf][0] = *(const bf16x8*)&LB[col * 64 + sw0];
      b1[nf][1] = *(const bf16x8*)&LB[col * 64 + sw1];
    }
    if (pf) stageA256(A, LA, 0, row0, K, kpf, w, lane);
    __builtin_amdgcn_s_barrier();
    asm volatile("s_waitcnt lgkmcnt(0)" ::: "memory");
    __builtin_amdgcn_sched_barrier(0);
    __builtin_amdgcn_s_setprio(1);
#pragma unroll
    for (int mf = 0; mf < 4; ++mf)
#pragma unroll
      for (int nf = 0; nf < 2; ++nf)
#pragma unroll
        for (int ks = 0; ks < 2; ++ks)
          acc[mf][2 + nf] = __builtin_amdgcn_mfma_f32_16x16x32_bf16(af[mf][ks], b1[nf][ks], acc[mf][2 + nf], 0, 0, 0);
    __builtin_amdgcn_s_setprio(0);
    __builtin_amdgcn_s_barrier();

    // phase 2: quadrant (1,0); stage Bq0(t+2)
#pragma unroll
    for (int mf = 0; mf < 4; ++mf) {
      int row = wm * 128 + 64 + mf * 16 + l15;
      af[mf][0] = *(const bf16x8*)&LA[row * 64 + sw0];
      af[mf][1] = *(const bf16x8*)&LA[row * 64 + sw1];
    }
    if (pf) stageB256(B, LB, 0, col0, K, kpf, w, lane);
    __builtin_amdgcn_s_barrier();
    asm volatile("s_waitcnt lgkmcnt(0)" ::: "memory");
    __builtin_amdgcn_sched_barrier(0);
    __builtin_amdgcn_s_setprio(1);
#pragma unroll
    for (int mf = 0; mf < 4; ++mf)
#pragma unroll
      for (int nf = 0; nf < 2; ++nf)
#pragma unroll
        for (int ks = 0; ks < 2; ++ks)
          acc[4 + mf][nf] = __builtin_amdgcn_mfma_f32_16x16x32_bf16(af[mf][ks], b0[nf][ks], acc[4 + mf][nf], 0, 0, 0);
    __builtin_amdgcn_s_setprio(0);
    __builtin_amdgcn_s_barrier();

    // phase 3: quadrant (1,1); stage Bq1+Aq1(t+2); boundary vmcnt after MFMA
    if (pf) {
      stageB256(B, LB, 1, col0, K, kpf, w, lane);
      stageA256(A, LA, 1, row0, K, kpf, w, lane);
    }
    __builtin_amdgcn_s_setprio(1);
#pragma unroll
    for (int mf = 0; mf < 4; ++mf)
#pragma unroll
      for (int nf = 0; nf < 2; ++nf)
#pragma unroll
        for (int ks = 0; ks < 2; ++ks)
          acc[4 + mf][2 + nf] = __builtin_amdgcn_mfma_f32_16x16x32_bf16(af[mf][ks], b1[nf][ks], acc[4 + mf][2 + nf], 0, 0, 0);
    __builtin_amdgcn_s_setprio(0);
    if (pf)               asm volatile("s_waitcnt vmcnt(8)" ::: "memory");
    else if (t + 1 < NT)  asm volatile("s_waitcnt vmcnt(0)" ::: "memory");
    __builtin_amdgcn_s_barrier();
  }

#pragma unroll
  for (int mf = 0; mf < 8; ++mf) {
    const int rb = row0 + wm * 128 + mf * 16 + l4 * 4;
#pragma unroll
    for (int nf = 0; nf < 4; ++nf) {
      const int c = col0 + wn * 64 + nf * 16 + l15;
      float bv = 0.f;
      if constexpr (EPI >= 1) bv = bias[c];
#pragma unroll
      for (int q = 0; q < 4; ++q) {
        float v = acc[mf][nf][q] + bv;
        size_t o = (size_t)(rb + q) * M + c;
        if constexpr (OBF) ((u16*)Cout)[o] = f2bf(v);
        else ((float*)Cout)[o] = v;
      }
    }
  }
}

// ---------------- fused causal attention, one WG per (qtile, h, b) ----------------
// No-max softmax (scores provably small: LN'd inputs x w=0.02 weights -> |s| < ~9),
// deferred l-reduce, causal partial staging, XOR bank-swizzles on K/Vt/P.
__global__ __launch_bounds__(256, 1) void attn_kernel(const u16* __restrict__ qkv,
                                                      const u16* __restrict__ vtg,
                                                      u16* __restrict__ att) {
  __shared__ u16 Kl[S * HD];        // [s][64]  slot-swizzled
  __shared__ u16 Vt[HD * S];        // [64][nkv] packed, slot-swizzled
  __shared__ u16 Pl[4][32 * 64];    // per-wave P scratch, col-swizzled
  const int tid = threadIdx.x, lane = tid & 63, w = tid >> 6;
  const int qt = blockIdx.x, h = blockIdx.y, b = blockIdx.z;
  const int l15 = lane & 15, l4 = lane >> 4;

  const int nkv = (qt >= 2) ? 512 : (128 << qt);       // Vt cols staged (pow2), <= S
  const int sh = (qt == 0) ? 4 : (qt == 1) ? 5 : 6;    // log2(nkv/8)

  {
    const int sfl = tid * 8;
    // K rows [0, (qt+1)*128): source slot pre-swizzled by (s&7)
    for (int r = 0; r < (qt + 1) * 4; ++r) {
      int l = r * 2048 + sfl;
      int s = l >> 6;
      int slot = (l & 63) >> 3;
      int d = (slot ^ (s & 7)) << 3;
      gload16(qkv + (size_t)(s * Bb + b) * D3 + D + h * HD + d, &Kl[l]);
    }
    // Vt rows d=0..63, cols [0,nkv): packed stride nkv, source slot pre-swizzled by (d&7)
    const u16* vg = vtg + (size_t)(b * NH + h) * (HD * S);
    const int cpr_m1 = (nkv >> 3) - 1;
    for (int r = 0; r < (nkv >> 5); ++r) {
      int c = r * 256 + tid;
      int d = c >> sh, s8 = c & cpr_m1;
      int ss = (s8 ^ (d & 7)) << 3;
      gload16(vg + (size_t)d * S + ss, &Vt[c * 8]);
    }
  }
  asm volatile("s_waitcnt vmcnt(0)" ::: "memory");
  __syncthreads();

  const int qbase = qt * 128 + w * 32;
  bf16x8 qf[2][2];
#pragma unroll
  for (int fm = 0; fm < 2; ++fm)
#pragma unroll
    for (int kk = 0; kk < 2; ++kk) {
      int qs = qbase + fm * 16 + l15;
      qf[fm][kk] = *(const bf16x8*)(qkv + (size_t)(qs * Bb + b) * D3 + h * HD + kk * 32 + l4 * 8);
    }

  const int sw0 = ((0 * 4 + l4) ^ (l15 & 7)) * 8;   // swizzled slot base, ks=0
  const int sw1 = ((1 * 4 + l4) ^ (l15 & 7)) * 8;   // ks=1

  float lsum[2][4];
  f32x4 o[2][4] = {};
#pragma unroll
  for (int fm = 0; fm < 2; ++fm)
#pragma unroll
    for (int j = 0; j < 4; ++j) lsum[fm][j] = 0.f;

  const int nchunk = qbase / 64 + 1;
  for (int ch = 0; ch < nchunk; ++ch) {
    f32x4 sc[2][4] = {};
#pragma unroll
    for (int kk = 0; kk < 2; ++kk) {
      bf16x8 kb[4];
#pragma unroll
      for (int fn = 0; fn < 4; ++fn)
        kb[fn] = *(const bf16x8*)&Kl[(ch * 64 + fn * 16 + l15) * 64 + (kk ? sw1 : sw0)];
#pragma unroll
      for (int fm = 0; fm < 2; ++fm)
#pragma unroll
        for (int fn = 0; fn < 4; ++fn)
          sc[fm][fn] = __builtin_amdgcn_mfma_f32_16x16x32_bf16(qf[fm][kk], kb[fn], sc[fm][fn], 0, 0, 0);
    }
    // P = exp(s/8) (no max subtraction), causal zero only on the diagonal chunk
    const bool mk = (ch == nchunk - 1);
    u16* P = &Pl[w][0];
#pragma unroll
    for (int fm = 0; fm < 2; ++fm)
#pragma unroll
      for (int j = 0; j < 4; ++j) {
        const int rlow = l4 * 4 + j;
        const int q_s = qbase + fm * 16 + rlow;
        const int cswz = (rlow & 7) << 3;
#pragma unroll
        for (int fn = 0; fn < 4; ++fn) {
          float p = __expf(sc[fm][fn][j] * 0.125f);
          if (mk) {
            int k_s = ch * 64 + fn * 16 + l15;
            if (k_s > q_s) p = 0.f;
          }
          lsum[fm][j] += p;
          P[(fm * 16 + rlow) * 64 + ((fn * 16 + l15) ^ cswz)] = f2bf(p);
        }
      }
    asm volatile("" ::: "memory");
#pragma unroll
    for (int kk = 0; kk < 2; ++kk) {
      bf16x8 pa[2];
#pragma unroll
      for (int fm = 0; fm < 2; ++fm)
        pa[fm] = *(const bf16x8*)&P[(fm * 16 + l15) * 64 + ((kk * 32 + l4 * 8) ^ ((l15 & 7) << 3))];
#pragma unroll
      for (int fd = 0; fd < 4; ++fd) {
        bf16x8 vb = *(const bf16x8*)&Vt[(fd * 16 + l15) * nkv + (((ch * 8 + kk * 4 + l4) ^ (l15 & 7)) << 3)];
#pragma unroll
        for (int fm = 0; fm < 2; ++fm)
          o[fm][fd] = __builtin_amdgcn_mfma_f32_16x16x32_bf16(pa[fm], vb, o[fm][fd], 0, 0, 0);
      }
    }
    asm volatile("" ::: "memory");
  }
  // one deferred reduce of l over the 16-lane key groups
  for (int off = 1; off <= 8; off <<= 1)
#pragma unroll
    for (int fm = 0; fm < 2; ++fm)
#pragma unroll
      for (int j = 0; j < 4; ++j)
        lsum[fm][j] += __shfl_xor(lsum[fm][j], off);
#pragma unroll
  for (int fm = 0; fm < 2; ++fm)
#pragma unroll
    for (int fd = 0; fd < 4; ++fd)
#pragma unroll
      for (int j = 0; j < 4; ++j) {
        int s = qbase + fm * 16 + l4 * 4 + j;
        int d = h * HD + fd * 16 + l15;
        att[(size_t)(s * Bb + b) * D + d] = f2bf(o[fm][fd][j] / lsum[fm][j]);
      }
}

extern "C" void kernel_launch(void* const* d_in, const int* in_sizes, int n_in,
                              void* d_out, int out_size, void* d_ws, size_t ws_size,
                              hipStream_t stream) {
  const int* src = (const int*)d_in[0];
  const float* emb = (const float*)d_in[1];
  const float* em = (const float*)d_in[2];
  const float* qkvw = (const float*)d_in[3];
  const float* qkvb = (const float*)d_in[4];
  const float* ow = (const float*)d_in[5];
  const float* ob = (const float*)d_in[6];
  const float* w1 = (const float*)d_in[7];
  const float* b1 = (const float*)d_in[8];
  const float* w2 = (const float*)d_in[9];
  const float* b2 = (const float*)d_in[10];
  const float* ln1g = (const float*)d_in[11];
  const float* ln1b = (const float*)d_in[12];
  const float* ln2g = (const float*)d_in[13];
  const float* ln2b = (const float*)d_in[14];
  const float* decw = (const float*)d_in[15];
  const float* decb = (const float*)d_in[16];
  float* out = (float*)d_out;

  uint8_t* ws = (uint8_t*)d_ws;
  size_t off = 0;
  auto alloc = [&](size_t bytes) -> void* {
    void* p = ws + off;
    off += (bytes + 255) & ~(size_t)255;
    return p;
  };
  u16* decw_bf = (u16*)alloc((size_t)V * D * 2);
  u16* lw_qkv  = (u16*)alloc((size_t)D3 * D * 2);
  u16* lw_o    = (u16*)alloc((size_t)D * D * 2);
  u16* lw_1    = (u16*)alloc((size_t)D * D * 2);
  u16* lw_2    = (u16*)alloc((size_t)D * D * 2);
  u16* em_bf   = (u16*)alloc((size_t)D * D * 2);
  u16* emT_bf  = (u16*)alloc((size_t)D * D * 2);
  u16* xe_bf   = (u16*)alloc((size_t)N * D * 2);
  float* x_f   = (float*)alloc((size_t)N * D * 4);
  u16* x_bf    = (u16*)alloc((size_t)N * D * 2);
  u16* tmp_bf  = (u16*)alloc((size_t)N * D * 2);
  u16* qkv_bf  = (u16*)alloc((size_t)N * D3 * 2);
  u16* vtg     = (u16*)alloc((size_t)N * D * 2);
  u16* att_bf  = (u16*)alloc((size_t)N * D * 2);
  u16* h_bf    = (u16*)alloc((size_t)N * D * 2);
  u16* pred_bf = (u16*)alloc((size_t)N * D * 2);
  (void)ws_size; (void)in_sizes; (void)n_in; (void)out_size;

  cvt_kernel<<<1024, 256, 0, stream>>>(em, em_bf, D * D / 4);
  transpose_cvt<<<dim3(32, 32), 256, 0, stream>>>(em, emT_bf);
  gather_kernel<<<N * D / 1024, 256, 0, stream>>>(src, emb, xe_bf);
  // embed GEMM + fused sinusoidal PE -> x_f (f32) + x_bf (bf16)
  gemm64<3, false><<<dim3(D / 128, N / 64), 256, 0, stream>>>(xe_bf, em_bf, nullptr, x_f, x_bf, D, D);

  const int nqkv4 = D3 * D / 4;
  const int ndd4 = D * D / 4;
  for (int l = 0; l < L; ++l) {
    cvt4_kernel<<<(nqkv4 + 3 * ndd4) / 256, 256, 0, stream>>>(
        qkvw + (size_t)l * D3 * D, ow + (size_t)l * D * D,
        w1 + (size_t)l * D * D, w2 + (size_t)l * D * D,
        lw_qkv, lw_o, lw_1, lw_2, nqkv4, ndd4, ndd4);

    gemm256<1, true><<<(D3 / 256) * (N / 256), 512, 0, stream>>>(x_bf, lw_qkv, qkvb + l * D3, qkv_bf, D3, D);
    vtrans_kernel<<<dim3(S / 64, Bb * NH), 256, 0, stream>>>(qkv_bf, vtg);
    attn_kernel<<<dim3(S / 128, NH, Bb), 256, 0, stream>>>(qkv_bf, vtg, att_bf);
    gemm64<1, true><<<dim3(D / 128, N / 64), 256, 0, stream>>>(att_bf, lw_o, ob + l * D, tmp_bf, nullptr, D, D);
    ln_kernel<<<N / 4, 256, 0, stream>>>(x_f, tmp_bf, ln1g + l * D, ln1b + l * D, x_f, x_bf);
    gemm64<2, true><<<dim3(D / 128, N / 64), 256, 0, stream>>>(x_bf, lw_1, b1 + l * D, h_bf, nullptr, D, D);
    gemm64<1, true><<<dim3(D / 128, N / 64), 256, 0, stream>>>(h_bf, lw_2, b2 + l * D, tmp_bf, nullptr, D, D);
    ln_kernel<<<N / 4, 256, 0, stream>>>(x_f, tmp_bf, ln2g + l * D, ln2b + l * D, x_f, x_bf);
  }

  gemm64<0, true><<<dim3(D / 128, N / 64), 256, 0, stream>>>(x_bf, emT_bf, nullptr, pred_bf, nullptr, D, D);
  cvt_kernel<<<(size_t)V * D / 1024, 256, 0, stream>>>(decw, decw_bf, V * D / 4);
  gemm256<1, false><<<(V / 256) * (N / 256), 512, 0, stream>>>(pred_bf, decw_bf, decb, out, V, D);
}